// Round 5
// baseline (527.415 us; speedup 1.0000x reference)
//
#include <hip/hip_runtime.h>
#include <hip/hip_bf16.h>

// Dims
#define B_  16
#define T_  256
#define C_  64
#define F_  128
#define O_  32   // GO
#define H_  32
#define G4_ 128  // 4*H

typedef __attribute__((ext_vector_type(8))) short bfrag;
typedef __attribute__((ext_vector_type(4))) float f4acc;

__device__ __forceinline__ unsigned short f2bf(float v) {
    union { float f; unsigned u; } c; c.f = v;
    unsigned r = c.u + 0x7FFF + ((c.u >> 16) & 1);
    return (unsigned short)(r >> 16);
}
__device__ __forceinline__ float bf2f(unsigned short b) {
    union { float f; unsigned u; } c; c.u = ((unsigned)b) << 16; return c.f;
}
__device__ __forceinline__ float sigm_f(float x) {
    return __builtin_amdgcn_rcpf(1.f + __expf(-x));
}
__device__ __forceinline__ float tanh_f(float x) {
    float e = __expf(2.f * x);
    return 1.f - 2.f * __builtin_amdgcn_rcpf(e + 1.f);
}
__device__ __forceinline__ float readlane_f(float v, int l) {
    return __int_as_float(__builtin_amdgcn_readlane(__float_as_int(v), l));
}

// ---------------------------------------------------------------------------
// K0: softmax of spectral_w rows (64 rows of 128)
// ---------------------------------------------------------------------------
__global__ __launch_bounds__(64) void k_sw(const float* __restrict__ w,
                                           float* __restrict__ sw) {
    int c = blockIdx.x, lane = threadIdx.x;
    const float* row = w + c * F_;
    float v0 = row[lane], v1 = row[lane + 64];
    float m = fmaxf(v0, v1);
#pragma unroll
    for (int s = 1; s < 64; s <<= 1) m = fmaxf(m, __shfl_xor(m, s));
    float e0 = __expf(v0 - m), e1 = __expf(v1 - m);
    float s = e0 + e1;
#pragma unroll
    for (int s_ = 1; s_ < 64; s_ <<= 1) s += __shfl_xor(s, s_);
    sw[c * F_ + lane] = e0 / s;
    sw[c * F_ + lane + 64] = e1 / s;
}

// ---------------------------------------------------------------------------
// K1: MFMA phase1. split-bf16 (hi/lo) Hn planes in LDS.
// grid (B, T/TCP), block 256. TCP=2: 2048 blocks = 8 blocks/CU of work with
// 4 resident -> desynchronized blocks overlap load bursts with MFMA phases.
// ---------------------------------------------------------------------------
#define TCP 2
#define PSTR 136   // bf16 elements per row (272 B): 16B-aligned, bank-uniform

#define MFMA16(a, b, c) __builtin_amdgcn_mfma_f32_16x16x32_bf16(a, b, c, 0, 0, 0)

__global__ __launch_bounds__(256) void k_phase1(
    const float* __restrict__ x, const float* __restrict__ sw,
    const float* __restrict__ gat_W, const float* __restrict__ gat_a,
    float* __restrict__ A, float* __restrict__ Wh,
    float* __restrict__ s1, float* __restrict__ s2) {
    const int b = blockIdx.x, tc = blockIdx.y, tid = threadIdx.x;
    const int wv = tid >> 6, lane = tid & 63;
    const int quad = lane >> 4, l16 = lane & 15;

    __shared__ unsigned short hhi[64 * PSTR];
    __shared__ unsigned short hlo[64 * PSTR];
    __shared__ float nrm[64];
    __shared__ float s1p[2][64], s2p[2][64];

    // sw regs (same (c,f) slice every t)
    float4 swr[8];
    {
        const float4* sw4 = (const float4*)sw;
#pragma unroll
        for (int i = 0; i < 8; i++) swr[i] = sw4[tid + 256 * i];
    }

    const int rt0 = (wv >> 1) * 2;  // row-tile base {0,2}
    const int ct0 = (wv & 1) * 2;   // col-tile base {0,2}
    const int jW = wv & 1;          // Wh col-tile

    // W fragments (hi/lo) for this wave's jW, ksteps 0..3, held in regs
    bfrag wfh[4], wfl[4];
    {
        const int n = l16 + 16 * jW;
#pragma unroll
        for (int k = 0; k < 4; k++) {
            union { unsigned short u[8]; bfrag v; } Hu, Lu;
#pragma unroll
            for (int u = 0; u < 8; u++) {
                float v = gat_W[(32 * k + quad * 8 + u) * O_ + n];
                unsigned short hb = f2bf(v);
                Hu.u[u] = hb;
                Lu.u[u] = f2bf(v - bf2f(hb));
            }
            wfh[k] = Hu.v;
            wfl[k] = Lu.v;
        }
    }
    const float ga1 = gat_a[l16 + 16 * jW];
    const float ga2 = gat_a[O_ + l16 + 16 * jW];

    f4acc accA[2][2];
#pragma unroll
    for (int i = 0; i < 2; i++)
#pragma unroll
        for (int j = 0; j < 2; j++) accA[i][j] = (f4acc){0.f, 0.f, 0.f, 0.f};

    for (int tt = 0; tt < TCP; ++tt) {
        const int t = tc * TCP + tt;
        const float4* xg = (const float4*)(x + ((size_t)(b * T_ + t) << 13));
        float4 xr[8];
#pragma unroll
        for (int i = 0; i < 8; i++) xr[i] = xg[tid + 256 * i];

        float invn_[8];
#pragma unroll
        for (int i = 0; i < 8; i++) {
            float4 v = xr[i], s = swr[i];
            v.x *= s.x; v.y *= s.y; v.z *= s.z; v.w *= s.w;
            xr[i] = v;
            float ss = v.x * v.x + v.y * v.y + v.z * v.z + v.w * v.w;
#pragma unroll
            for (int d = 1; d < 32; d <<= 1) ss += __shfl_xor(ss, d);
            float nv = sqrtf(ss) + 1e-8f;
            invn_[i] = 1.0f / nv;
            if ((tid & 31) == 0) nrm[(tid >> 5) + 8 * i] = nv;
        }
        // split + write planes: row c=(tid>>5)+8i, f = 4*(tid&31)
#pragma unroll
        for (int i = 0; i < 8; i++) {
            int c = (tid >> 5) + 8 * i;
            float4 v = xr[i];
            float iv = invn_[i];
            float a0 = v.x * iv, a1 = v.y * iv, a2 = v.z * iv, a3 = v.w * iv;
            union { unsigned short u[4]; unsigned long long q; } Hq, Lq;
            unsigned short h0 = f2bf(a0), h1 = f2bf(a1), h2 = f2bf(a2), h3 = f2bf(a3);
            Hq.u[0] = h0; Hq.u[1] = h1; Hq.u[2] = h2; Hq.u[3] = h3;
            Lq.u[0] = f2bf(a0 - bf2f(h0));
            Lq.u[1] = f2bf(a1 - bf2f(h1));
            Lq.u[2] = f2bf(a2 - bf2f(h2));
            Lq.u[3] = f2bf(a3 - bf2f(h3));
            int off = c * PSTR + 4 * (tid & 31);
            *(unsigned long long*)&hhi[off] = Hq.q;
            *(unsigned long long*)&hlo[off] = Lq.q;
        }
        __syncthreads();  // (b) planes ready

        f4acc accW0 = (f4acc){0.f, 0.f, 0.f, 0.f};
        f4acc accW1 = (f4acc){0.f, 0.f, 0.f, 0.f};
#pragma unroll
        for (int k = 0; k < 4; k++) {
            const int ko = 32 * k + 8 * quad;
            bfrag r0h = *(const bfrag*)&hhi[(rt0 * 16 + l16) * PSTR + ko];
            bfrag r0l = *(const bfrag*)&hlo[(rt0 * 16 + l16) * PSTR + ko];
            bfrag r1h = *(const bfrag*)&hhi[((rt0 + 1) * 16 + l16) * PSTR + ko];
            bfrag r1l = *(const bfrag*)&hlo[((rt0 + 1) * 16 + l16) * PSTR + ko];
            bfrag c0h = *(const bfrag*)&hhi[(ct0 * 16 + l16) * PSTR + ko];
            bfrag c0l = *(const bfrag*)&hlo[(ct0 * 16 + l16) * PSTR + ko];
            bfrag c1h = *(const bfrag*)&hhi[((ct0 + 1) * 16 + l16) * PSTR + ko];
            bfrag c1l = *(const bfrag*)&hlo[((ct0 + 1) * 16 + l16) * PSTR + ko];
            // A quadrant: 4 tiles x 3 products
            accA[0][0] = MFMA16(r0h, c0h, accA[0][0]);
            accA[0][0] = MFMA16(r0h, c0l, accA[0][0]);
            accA[0][0] = MFMA16(r0l, c0h, accA[0][0]);
            accA[0][1] = MFMA16(r0h, c1h, accA[0][1]);
            accA[0][1] = MFMA16(r0h, c1l, accA[0][1]);
            accA[0][1] = MFMA16(r0l, c1h, accA[0][1]);
            accA[1][0] = MFMA16(r1h, c0h, accA[1][0]);
            accA[1][0] = MFMA16(r1h, c0l, accA[1][0]);
            accA[1][0] = MFMA16(r1l, c0h, accA[1][0]);
            accA[1][1] = MFMA16(r1h, c1h, accA[1][1]);
            accA[1][1] = MFMA16(r1h, c1l, accA[1][1]);
            accA[1][1] = MFMA16(r1l, c1h, accA[1][1]);
            // Wh tiles (rows rt0, rt0+1; col jW), W frags in regs
            accW0 = MFMA16(r0h, wfh[k], accW0);
            accW0 = MFMA16(r0h, wfl[k], accW0);
            accW0 = MFMA16(r0l, wfh[k], accW0);
            accW1 = MFMA16(r1h, wfh[k], accW1);
            accW1 = MFMA16(r1h, wfl[k], accW1);
            accW1 = MFMA16(r1l, wfh[k], accW1);
        }
        // epilogue: scale rows by nrm, write Wh, reduce s1/s2 per row
        float* whout = Wh + (size_t)(b * T_ + t) * (C_ * O_);
#pragma unroll
        for (int i2 = 0; i2 < 2; i2++) {
            f4acc aw = i2 ? accW1 : accW0;
#pragma unroll
            for (int r = 0; r < 4; r++) {
                int row = (rt0 + i2) * 16 + quad * 4 + r;
                float val = aw[r] * nrm[row];
                whout[row * O_ + l16 + 16 * jW] = val;
                float v1 = val * ga1, v2 = val * ga2;
#pragma unroll
                for (int d = 1; d < 16; d <<= 1) {
                    v1 += __shfl_xor(v1, d);
                    v2 += __shfl_xor(v2, d);
                }
                if (l16 == 0) { s1p[jW][row] = v1; s2p[jW][row] = v2; }
            }
        }
        __syncthreads();  // (c) s1p/s2p ready; also: this-t frag reads done
        if (tid < 64) {
            s1[(b * T_ + t) * C_ + tid] = s1p[0][tid] + s1p[1][tid];
            s2[(b * T_ + t) * C_ + tid] = s2p[0][tid] + s2p[1][tid];
        }
    }
    // block-end: quadrants disjoint -> direct atomicAdd
#pragma unroll
    for (int i2 = 0; i2 < 2; i2++)
#pragma unroll
        for (int j2 = 0; j2 < 2; j2++)
#pragma unroll
            for (int r = 0; r < 4; r++) {
                int row = (rt0 + i2) * 16 + quad * 4 + r;
                int col = (ct0 + j2) * 16 + l16;
                atomicAdd(&A[b * (C_ * C_) + row * C_ + col], accA[i2][j2][r]);
            }
}

// ---------------------------------------------------------------------------
// K2: top-4 selection + symmetrize -> amask bitmask per (b,c). grid B, block 64
// ---------------------------------------------------------------------------
__global__ __launch_bounds__(64) void k_topk(const float* __restrict__ A,
                                             unsigned long long* __restrict__ amask) {
    int b = blockIdx.x;
    int c = threadIdx.x;
    __shared__ unsigned long long tk[C_];
    const float* row = A + b * (C_ * C_) + c * C_;
    unsigned long long sel = 0ULL;
    for (int r = 0; r < 4; r++) {
        float best = -1e30f;
        int bi = 0;
        for (int d = 0; d < C_; d++) {
            if (sel & (1ULL << d)) continue;
            float v = row[d];
            if (v > best) { best = v; bi = d; }
        }
        sel |= (1ULL << bi);
    }
    unsigned long long t = sel & ~(1ULL << c);
    tk[c] = t;
    __syncthreads();
    unsigned long long sym = t;
    for (int d = 0; d < C_; d++)
        if ((tk[d] >> c) & 1ULL) sym |= (1ULL << d);
    unsigned long long m = (1ULL << c);
    unsigned long long s2 = sym;
    while (s2) {
        int d = __ffsll(s2) - 1;
        s2 &= s2 - 1;
        if (row[d] > 0.f) m |= (1ULL << d);
    }
    amask[b * C_ + c] = m;
}

// ---------------------------------------------------------------------------
// K3: GAT attention + relu + pooling + FUSED lstm input projection.
// block 256 = 4 waves = 4 t's. grid B*T/4.
// gx is written GATE-COLUMN-MAJOR: gxT[dir][b][col][t] (t contiguous), and
// for dir=1 already TIME-REVERSED (written at 255-t), so k_lstm_seq reads
// forward contiguous float4s regardless of direction. Per-gate accumulation
// order unchanged -> bitwise-identical values.
// ---------------------------------------------------------------------------
__global__ __launch_bounds__(256) void k_gat(
    const float* __restrict__ Wh, const float* __restrict__ s1,
    const float* __restrict__ s2, const unsigned long long* __restrict__ amask,
    const float* __restrict__ pool_w, const float* __restrict__ pool_b,
    const float* __restrict__ Wi_f, const float* __restrict__ b_f,
    const float* __restrict__ Wi_r, const float* __restrict__ b_r,
    float* __restrict__ gx) {
    int tg = blockIdx.x;
    int wv = threadIdx.x >> 6, c = threadIdx.x & 63;
    int bt = tg * 4 + wv;
    int b = bt >> 8;
    __shared__ float buf[4][C_][33];
    __shared__ float s2s[4][C_];
    __shared__ float hp[4][H_];

    s2s[wv][c] = s2[bt * C_ + c];
    float s1c = s1[bt * C_ + c];
    unsigned long long m = amask[b * C_ + c];
    __syncthreads();

    float mx = -1e30f;
    unsigned long long mm = m;
    while (mm) {
        int d = __ffsll(mm) - 1; mm &= mm - 1;
        float v = s1c + s2s[wv][d];
        v = v > 0.f ? v : 0.2f * v;
        mx = fmaxf(mx, v);
    }
    float ssum = 0.f;
    mm = m;
    while (mm) {
        int d = __ffsll(mm) - 1; mm &= mm - 1;
        float v = s1c + s2s[wv][d];
        v = v > 0.f ? v : 0.2f * v;
        ssum += __expf(v - mx);
    }
    float inv = 1.0f / ssum;
    float g[O_];
#pragma unroll
    for (int i = 0; i < O_; i++) g[i] = 0.f;
    mm = m;
    while (mm) {
        int d = __ffsll(mm) - 1; mm &= mm - 1;
        float v = s1c + s2s[wv][d];
        v = v > 0.f ? v : 0.2f * v;
        float a = __expf(v - mx);
        const float4* wr = (const float4*)(Wh + (size_t)bt * (C_ * O_) + d * O_);
#pragma unroll
        for (int q = 0; q < 8; q++) {
            float4 w4 = wr[q];
            g[4 * q + 0] += a * w4.x;
            g[4 * q + 1] += a * w4.y;
            g[4 * q + 2] += a * w4.z;
            g[4 * q + 3] += a * w4.w;
        }
    }
    float lg = pool_b[0];
#pragma unroll
    for (int i = 0; i < O_; i++) {
        g[i] = fmaxf(g[i] * inv, 0.f);
        lg += g[i] * pool_w[i];
    }
    float wmx = lg;
#pragma unroll
    for (int s = 1; s < 64; s <<= 1) wmx = fmaxf(wmx, __shfl_xor(wmx, s));
    float we = __expf(lg - wmx);
    float wsum = we;
#pragma unroll
    for (int s = 1; s < 64; s <<= 1) wsum += __shfl_xor(wsum, s);
    float wcf = we / wsum;
#pragma unroll
    for (int i = 0; i < O_; i++) buf[wv][c][i] = g[i] * wcf;
    __syncthreads();
    {
        int wt = threadIdx.x >> 6, o = threadIdx.x & 31, hf = (threadIdx.x >> 5) & 1;
        float sacc = 0.f;
#pragma unroll 8
        for (int d = hf * 32; d < hf * 32 + 32; d++) sacc += buf[wt][d][o];
        sacc += __shfl_xor(sacc, 32);
        if (hf == 0) hp[wt][o] = sacc;
    }
    __syncthreads();
    // fused lstm_pre: thread = (dir = tid>>7, col = tid&127)
    {
        int dir = threadIdx.x >> 7, col = threadIdx.x & 127;
        const float* Wi = dir ? Wi_r : Wi_f;
        const float* bb = dir ? b_r : b_f;
        float bv = bb[col];
        float a0 = bv, a1 = bv, a2 = bv, a3 = bv;
#pragma unroll
        for (int k = 0; k < H_; k++) {
            float wvv = Wi[k * G4_ + col];
            a0 = fmaf(hp[0][k], wvv, a0);
            a1 = fmaf(hp[1][k], wvv, a1);
            a2 = fmaf(hp[2][k], wvv, a2);
            a3 = fmaf(hp[3][k], wvv, a3);
        }
        int b0 = (tg * 4) >> 8;
        int t0 = (tg * 4) & 255;
        float* cb = gx + ((size_t)(dir * B_ + b0) * G4_ + col) * T_;
        if (dir == 0) {
            *(float4*)(cb + t0) = make_float4(a0, a1, a2, a3);
        } else {
            *(float4*)(cb + (252 - t0)) = make_float4(a3, a2, a1, a0);
        }
    }
}

// ---------------------------------------------------------------------------
// K4b: LSTM recurrence — DUAL-DIRECTION per wave. grid B_, block 64.
// Round-3/4 lesson: neither rolling nor burst prefetch moved the needle
// (93/111/107us) -> never load-bound. One lone wave per CU exposes every
// dependent-VALU / trans / ds_bpermute latency in the serial h-chain with
// nothing to fill the bubbles (VALU duty ~12% on active CUs). Fix: fwd and
// rev LSTMs are INDEPENDENT recurrences -> run both in ONE wave. The two
// chains interleave and fill each other's stall cycles (software SMT).
// Per-dir FP accumulation order unchanged -> bitwise-identical hcat.
// VGPR: 256 (both dirs' weights) + 64 (bursts) + temps ~ 350 < 450 spill line.
// ---------------------------------------------------------------------------
#define WWF(k) float2 wf##k = make_float2(Whf[(k) * G4_ + lane], Whf[(k) * G4_ + lane + 64]);
#define WWR(k) float2 wr##k = make_float2(Whr[(k) * G4_ + lane], Whr[(k) * G4_ + lane + 64]);
#define KSTD(k, Aq, hv, W) { float hk = readlane_f(hv, k); \
    Aq.x = fmaf(hk, W##k.x, Aq.x); Aq.y = fmaf(hk, W##k.y, Aq.y); }

#define STEP2(GF0, GF1, GR0, GR1) { \
    float2 A0f = make_float2(GF0, GF1); \
    float2 A1f = make_float2(0.f, 0.f), A2f = make_float2(0.f, 0.f), A3f = make_float2(0.f, 0.f); \
    float2 A0r = make_float2(GR0, GR1); \
    float2 A1r = make_float2(0.f, 0.f), A2r = make_float2(0.f, 0.f), A3r = make_float2(0.f, 0.f); \
    KSTD(0, A0f, hf, wf)  KSTD(0, A0r, hr, wr)  KSTD(1, A1f, hf, wf)  KSTD(1, A1r, hr, wr) \
    KSTD(2, A2f, hf, wf)  KSTD(2, A2r, hr, wr)  KSTD(3, A3f, hf, wf)  KSTD(3, A3r, hr, wr) \
    KSTD(4, A0f, hf, wf)  KSTD(4, A0r, hr, wr)  KSTD(5, A1f, hf, wf)  KSTD(5, A1r, hr, wr) \
    KSTD(6, A2f, hf, wf)  KSTD(6, A2r, hr, wr)  KSTD(7, A3f, hf, wf)  KSTD(7, A3r, hr, wr) \
    KSTD(8, A0f, hf, wf)  KSTD(8, A0r, hr, wr)  KSTD(9, A1f, hf, wf)  KSTD(9, A1r, hr, wr) \
    KSTD(10, A2f, hf, wf) KSTD(10, A2r, hr, wr) KSTD(11, A3f, hf, wf) KSTD(11, A3r, hr, wr) \
    KSTD(12, A0f, hf, wf) KSTD(12, A0r, hr, wr) KSTD(13, A1f, hf, wf) KSTD(13, A1r, hr, wr) \
    KSTD(14, A2f, hf, wf) KSTD(14, A2r, hr, wr) KSTD(15, A3f, hf, wf) KSTD(15, A3r, hr, wr) \
    KSTD(16, A0f, hf, wf) KSTD(16, A0r, hr, wr) KSTD(17, A1f, hf, wf) KSTD(17, A1r, hr, wr) \
    KSTD(18, A2f, hf, wf) KSTD(18, A2r, hr, wr) KSTD(19, A3f, hf, wf) KSTD(19, A3r, hr, wr) \
    KSTD(20, A0f, hf, wf) KSTD(20, A0r, hr, wr) KSTD(21, A1f, hf, wf) KSTD(21, A1r, hr, wr) \
    KSTD(22, A2f, hf, wf) KSTD(22, A2r, hr, wr) KSTD(23, A3f, hf, wf) KSTD(23, A3r, hr, wr) \
    KSTD(24, A0f, hf, wf) KSTD(24, A0r, hr, wr) KSTD(25, A1f, hf, wf) KSTD(25, A1r, hr, wr) \
    KSTD(26, A2f, hf, wf) KSTD(26, A2r, hr, wr) KSTD(27, A3f, hf, wf) KSTD(27, A3r, hr, wr) \
    KSTD(28, A0f, hf, wf) KSTD(28, A0r, hr, wr) KSTD(29, A1f, hf, wf) KSTD(29, A1r, hr, wr) \
    KSTD(30, A2f, hf, wf) KSTD(30, A2r, hr, wr) KSTD(31, A3f, hf, wf) KSTD(31, A3r, hr, wr) \
    float g0f = (A0f.x + A1f.x) + (A2f.x + A3f.x); \
    float g1f = (A0f.y + A1f.y) + (A2f.y + A3f.y); \
    float g0r = (A0r.x + A1r.x) + (A2r.x + A3r.x); \
    float g1r = (A0r.y + A1r.y) + (A2r.y + A3r.y); \
    float sAf = sigm_f(g0f); \
    float uf = sigm_f(half_sel * g1f); \
    float sBf = (lane < 32) ? fmaf(2.f, uf, -1.f) : uf; \
    float sAr = sigm_f(g0r); \
    float ur = sigm_f(half_sel * g1r); \
    float sBr = (lane < 32) ? fmaf(2.f, ur, -1.f) : ur; \
    float sff = __shfl(sAf, (lane & 31) + 32); \
    float sof = __shfl(sBf, (lane & 31) + 32); \
    float sfr = __shfl(sAr, (lane & 31) + 32); \
    float sor = __shfl(sBr, (lane & 31) + 32); \
    cf = fmaf(sff, cf, sAf * sBf); \
    cr = fmaf(sfr, cr, sAr * sBr); \
    float hnf = sof * tanh_f(cf); \
    float hnr = sor * tanh_f(cr); \
    hf = hnf; hr = hnr; \
    if (lane < H_) { *hcf = hnf; *hcr = hnr; } \
    hcf += 2 * H_; hcr -= 2 * H_; \
}

__global__ void __attribute__((amdgpu_flat_work_group_size(64, 64)))
__attribute__((amdgpu_waves_per_eu(1, 1))) k_lstm_seq(
    const float* __restrict__ gx,
    const float* __restrict__ Whf, const float* __restrict__ Whr,
    float* __restrict__ hcat) {
    int b = blockIdx.x;
    int lane = threadIdx.x;
    WWF(0) WWF(1) WWF(2) WWF(3) WWF(4) WWF(5) WWF(6) WWF(7)
    WWF(8) WWF(9) WWF(10) WWF(11) WWF(12) WWF(13) WWF(14) WWF(15)
    WWF(16) WWF(17) WWF(18) WWF(19) WWF(20) WWF(21) WWF(22) WWF(23)
    WWF(24) WWF(25) WWF(26) WWF(27) WWF(28) WWF(29) WWF(30) WWF(31)
    WWR(0) WWR(1) WWR(2) WWR(3) WWR(4) WWR(5) WWR(6) WWR(7)
    WWR(8) WWR(9) WWR(10) WWR(11) WWR(12) WWR(13) WWR(14) WWR(15)
    WWR(16) WWR(17) WWR(18) WWR(19) WWR(20) WWR(21) WWR(22) WWR(23)
    WWR(24) WWR(25) WWR(26) WWR(27) WWR(28) WWR(29) WWR(30) WWR(31)

    // column-major gx: lane's two gate columns per dir, contiguous in s
    const float* pf0 = gx + ((size_t)b * G4_ + lane) * T_;
    const float* pf1 = pf0 + (size_t)64 * T_;
    const float* pr0 = gx + ((size_t)(B_ + b) * G4_ + lane) * T_;
    const float* pr1 = pr0 + (size_t)64 * T_;
    float* hcf = hcat + (size_t)(b * T_) * (2 * H_) + lane;             // dir0, t=0, fwd
    float* hcr = hcat + ((size_t)(b * T_) + T_ - 1) * (2 * H_) + H_ + lane;  // dir1, t=255, bwd

    float hf = 0.f, cf = 0.f, hr = 0.f, cr = 0.f;
    const float half_sel = (lane < 32) ? 2.f : 1.f;

    // burst 0
    float4 f0a = *(const float4*)(pf0 + 0), f0b = *(const float4*)(pf0 + 4);
    float4 f1a = *(const float4*)(pf1 + 0), f1b = *(const float4*)(pf1 + 4);
    float4 r0a = *(const float4*)(pr0 + 0), r0b = *(const float4*)(pr0 + 4);
    float4 r1a = *(const float4*)(pr1 + 0), r1b = *(const float4*)(pr1 + 4);

    for (int bi = 0; bi < 32; bi++) {
        // issue next-burst loads (wrap on last iter: harmless, branch-free)
        int o = (8 * (bi + 1)) & 255;
        float4 nf0a = *(const float4*)(pf0 + o), nf0b = *(const float4*)(pf0 + o + 4);
        float4 nf1a = *(const float4*)(pf1 + o), nf1b = *(const float4*)(pf1 + o + 4);
        float4 nr0a = *(const float4*)(pr0 + o), nr0b = *(const float4*)(pr0 + o + 4);
        float4 nr1a = *(const float4*)(pr1 + o), nr1b = *(const float4*)(pr1 + o + 4);

        STEP2(f0a.x, f1a.x, r0a.x, r1a.x)
        STEP2(f0a.y, f1a.y, r0a.y, r1a.y)
        STEP2(f0a.z, f1a.z, r0a.z, r1a.z)
        STEP2(f0a.w, f1a.w, r0a.w, r1a.w)
        STEP2(f0b.x, f1b.x, r0b.x, r1b.x)
        STEP2(f0b.y, f1b.y, r0b.y, r1b.y)
        STEP2(f0b.z, f1b.z, r0b.z, r1b.z)
        STEP2(f0b.w, f1b.w, r0b.w, r1b.w)

        f0a = nf0a; f0b = nf0b; f1a = nf1a; f1b = nf1b;
        r0a = nr0a; r0b = nr0b; r1a = nr1a; r1b = nr1b;
    }
}

// ---------------------------------------------------------------------------
// K5: temporal attention + LN + fc1 + fc2 -> out (B,3). grid B, block 256.
// ---------------------------------------------------------------------------
__global__ __launch_bounds__(256) void k_final(
    const float* __restrict__ hcat,
    const float* __restrict__ taW, const float* __restrict__ tab,
    const float* __restrict__ tav,
    const float* __restrict__ lng, const float* __restrict__ lnb,
    const float* __restrict__ w1, const float* __restrict__ b1,
    const float* __restrict__ w2, const float* __restrict__ b2,
    float* __restrict__ out) {
    int b = blockIdx.x;
    int t = threadIdx.x;
    __shared__ float Wl[64 * 64];
    __shared__ float al[T_];
    __shared__ float wred[4];
    __shared__ float ctxp[4][64];
    __shared__ float ctx[64];
    __shared__ float a1[32];
    for (int i = t; i < 4096; i += 256) Wl[i] = taW[i];
    float4 hr[16];
    const float4* hb = (const float4*)(hcat + ((size_t)b * T_ + t) * 64);
#pragma unroll
    for (int i = 0; i < 16; i++) hr[i] = hb[i];
    __syncthreads();
    float sc = 0.f;
    for (int j = 0; j < 64; j++) {
        float s = tab[j];
#pragma unroll
        for (int k4 = 0; k4 < 16; k4++) {
            float4 h4 = hr[k4];
            const float* wcol = &Wl[(4 * k4) * 64 + j];
            s += h4.x * wcol[0] + h4.y * wcol[64] + h4.z * wcol[128] + h4.w * wcol[192];
        }
        sc += tanhf(s) * tav[j];
    }
    sc *= (1.0f / 1.5f);
    int wave = t >> 6, lane = t & 63;
    float m = sc;
#pragma unroll
    for (int s_ = 1; s_ < 64; s_ <<= 1) m = fmaxf(m, __shfl_xor(m, s_));
    if (lane == 0) wred[wave] = m;
    __syncthreads();
    m = fmaxf(fmaxf(wred[0], wred[1]), fmaxf(wred[2], wred[3]));
    float e = __expf(sc - m);
    float ssum = e;
#pragma unroll
    for (int s_ = 1; s_ < 64; s_ <<= 1) ssum += __shfl_xor(ssum, s_);
    __syncthreads();
    if (lane == 0) wred[wave] = ssum;
    __syncthreads();
    float S = wred[0] + wred[1] + wred[2] + wred[3];
    al[t] = e / S;
    __syncthreads();
    // ctx partials: thread = (part = t>>6, o = t&63)
    {
        int o = t & 63, part = t >> 6;
        float cacc = 0.f;
        for (int tt = part * 64; tt < part * 64 + 64; tt++)
            cacc += al[tt] * hcat[((size_t)b * T_ + tt) * 64 + o];
        ctxp[part][o] = cacc;
    }
    __syncthreads();
    if (t < 64) {
        float ctxo = ctxp[0][t] + ctxp[1][t] + ctxp[2][t] + ctxp[3][t];
        float sv = ctxo, sq = ctxo * ctxo;
#pragma unroll
        for (int s_ = 1; s_ < 64; s_ <<= 1) {
            sv += __shfl_xor(sv, s_);
            sq += __shfl_xor(sq, s_);
        }
        float mu = sv * (1.f / 64.f);
        float var = sq * (1.f / 64.f) - mu * mu;
        ctx[t] = (ctxo - mu) / sqrtf(var + 1e-5f) * lng[t] + lnb[t];
    }
    __syncthreads();
    if (t < 32) {
        float s = b1[t];
        for (int k = 0; k < 64; k++) s += ctx[k] * w1[k * 32 + t];
        a1[t] = fmaxf(s, 0.f);
    }
    __syncthreads();
    if (t < 3) {
        float s = b2[t];
        for (int k = 0; k < 32; k++) s += a1[k] * w2[k * 3 + t];
        out[b * 3 + t] = s;
    }
}

// ---------------------------------------------------------------------------
extern "C" void kernel_launch(void* const* d_in, const int* in_sizes, int n_in,
                              void* d_out, int out_size, void* d_ws, size_t ws_size,
                              hipStream_t stream) {
    const float* x          = (const float*)d_in[0];
    const float* spectral_w = (const float*)d_in[1];
    const float* gat_W      = (const float*)d_in[2];
    const float* gat_a      = (const float*)d_in[3];
    const float* pool_w     = (const float*)d_in[4];
    const float* pool_b     = (const float*)d_in[5];
    const float* lstm_Wi_f  = (const float*)d_in[6];
    const float* lstm_Wh_f  = (const float*)d_in[7];
    const float* lstm_b_f   = (const float*)d_in[8];
    const float* lstm_Wi_r  = (const float*)d_in[9];
    const float* lstm_Wh_r  = (const float*)d_in[10];
    const float* lstm_b_r   = (const float*)d_in[11];
    const float* ta_W       = (const float*)d_in[12];
    const float* ta_b       = (const float*)d_in[13];
    const float* ta_v       = (const float*)d_in[14];
    const float* ln_g       = (const float*)d_in[15];
    const float* ln_b       = (const float*)d_in[16];
    const float* fc1_w      = (const float*)d_in[17];
    const float* fc1_b      = (const float*)d_in[18];
    const float* fc2_w      = (const float*)d_in[19];
    const float* fc2_b      = (const float*)d_in[20];
    float* out = (float*)d_out;

    float* ws = (float*)d_ws;
    float* sw    = ws + 0;                         // 8192
    float* A     = ws + 8192;                      // 65536
    unsigned long long* amask = (unsigned long long*)(ws + 73728);  // 1024 u64
    float* Wh    = ws + 75776;                     // 8388608
    float* s1    = ws + 8464384;                   // 262144
    float* s2    = ws + 8726528;                   // 262144
    float* gx    = ws + 9119744;                   // 1048576 (column-major gxT)
    float* hcat  = ws + 10168320;                  // 262144

    hipMemsetAsync(A, 0, (size_t)C_ * C_ * B_ * sizeof(float), stream);
    k_sw<<<C_, 64, 0, stream>>>(spectral_w, sw);
    k_phase1<<<dim3(B_, T_ / TCP), 256, 0, stream>>>(x, sw, gat_W, gat_a, A, Wh, s1, s2);
    k_topk<<<B_, 64, 0, stream>>>(A, amask);
    k_gat<<<B_ * T_ / 4, 256, 0, stream>>>(Wh, s1, s2, amask, pool_w, pool_b,
                                           lstm_Wi_f, lstm_b_f, lstm_Wi_r, lstm_b_r, gx);
    k_lstm_seq<<<B_, 64, 0, stream>>>(gx, lstm_Wh_f, lstm_Wh_r, hcat);
    k_final<<<B_, 256, 0, stream>>>(hcat, ta_W, ta_b, ta_v, ln_g, ln_b,
                                    fc1_w, fc1_b, fc2_w, fc2_b, out);
}

// Round 6
// 522.152 us; speedup vs baseline: 1.0101x; 1.0101x over previous
//
#include <hip/hip_runtime.h>
#include <hip/hip_bf16.h>

// Dims
#define B_  16
#define T_  256
#define C_  64
#define F_  128
#define O_  32   // GO
#define H_  32
#define G4_ 128  // 4*H

typedef __attribute__((ext_vector_type(8))) short bfrag;
typedef __attribute__((ext_vector_type(4))) float f4acc;

__device__ __forceinline__ unsigned short f2bf(float v) {
    union { float f; unsigned u; } c; c.f = v;
    unsigned r = c.u + 0x7FFF + ((c.u >> 16) & 1);
    return (unsigned short)(r >> 16);
}
__device__ __forceinline__ float bf2f(unsigned short b) {
    union { float f; unsigned u; } c; c.u = ((unsigned)b) << 16; return c.f;
}
__device__ __forceinline__ float sigm_f(float x) {
    return __builtin_amdgcn_rcpf(1.f + __expf(-x));
}
__device__ __forceinline__ float tanh_f(float x) {
    float e = __expf(2.f * x);
    return 1.f - 2.f * __builtin_amdgcn_rcpf(e + 1.f);
}

// ---------------------------------------------------------------------------
// K0: softmax of spectral_w rows (64 rows of 128)
// ---------------------------------------------------------------------------
__global__ __launch_bounds__(64) void k_sw(const float* __restrict__ w,
                                           float* __restrict__ sw) {
    int c = blockIdx.x, lane = threadIdx.x;
    const float* row = w + c * F_;
    float v0 = row[lane], v1 = row[lane + 64];
    float m = fmaxf(v0, v1);
#pragma unroll
    for (int s = 1; s < 64; s <<= 1) m = fmaxf(m, __shfl_xor(m, s));
    float e0 = __expf(v0 - m), e1 = __expf(v1 - m);
    float s = e0 + e1;
#pragma unroll
    for (int s_ = 1; s_ < 64; s_ <<= 1) s += __shfl_xor(s, s_);
    sw[c * F_ + lane] = e0 / s;
    sw[c * F_ + lane + 64] = e1 / s;
}

// ---------------------------------------------------------------------------
// K1: MFMA phase1. split-bf16 (hi/lo) Hn planes in LDS.
// grid (B, T/TCP), block 256. TCP=2: 2048 blocks = 8 blocks/CU of work with
// 4 resident -> desynchronized blocks overlap load bursts with MFMA phases.
// ---------------------------------------------------------------------------
#define TCP 2
#define PSTR 136   // bf16 elements per row (272 B): 16B-aligned, bank-uniform

#define MFMA16(a, b, c) __builtin_amdgcn_mfma_f32_16x16x32_bf16(a, b, c, 0, 0, 0)

__global__ __launch_bounds__(256) void k_phase1(
    const float* __restrict__ x, const float* __restrict__ sw,
    const float* __restrict__ gat_W, const float* __restrict__ gat_a,
    float* __restrict__ A, float* __restrict__ Wh,
    float* __restrict__ s1, float* __restrict__ s2) {
    const int b = blockIdx.x, tc = blockIdx.y, tid = threadIdx.x;
    const int wv = tid >> 6, lane = tid & 63;
    const int quad = lane >> 4, l16 = lane & 15;

    __shared__ unsigned short hhi[64 * PSTR];
    __shared__ unsigned short hlo[64 * PSTR];
    __shared__ float nrm[64];
    __shared__ float s1p[2][64], s2p[2][64];

    // sw regs (same (c,f) slice every t)
    float4 swr[8];
    {
        const float4* sw4 = (const float4*)sw;
#pragma unroll
        for (int i = 0; i < 8; i++) swr[i] = sw4[tid + 256 * i];
    }

    const int rt0 = (wv >> 1) * 2;  // row-tile base {0,2}
    const int ct0 = (wv & 1) * 2;   // col-tile base {0,2}
    const int jW = wv & 1;          // Wh col-tile

    // W fragments (hi/lo) for this wave's jW, ksteps 0..3, held in regs
    bfrag wfh[4], wfl[4];
    {
        const int n = l16 + 16 * jW;
#pragma unroll
        for (int k = 0; k < 4; k++) {
            union { unsigned short u[8]; bfrag v; } Hu, Lu;
#pragma unroll
            for (int u = 0; u < 8; u++) {
                float v = gat_W[(32 * k + quad * 8 + u) * O_ + n];
                unsigned short hb = f2bf(v);
                Hu.u[u] = hb;
                Lu.u[u] = f2bf(v - bf2f(hb));
            }
            wfh[k] = Hu.v;
            wfl[k] = Lu.v;
        }
    }
    const float ga1 = gat_a[l16 + 16 * jW];
    const float ga2 = gat_a[O_ + l16 + 16 * jW];

    f4acc accA[2][2];
#pragma unroll
    for (int i = 0; i < 2; i++)
#pragma unroll
        for (int j = 0; j < 2; j++) accA[i][j] = (f4acc){0.f, 0.f, 0.f, 0.f};

    for (int tt = 0; tt < TCP; ++tt) {
        const int t = tc * TCP + tt;
        const float4* xg = (const float4*)(x + ((size_t)(b * T_ + t) << 13));
        float4 xr[8];
#pragma unroll
        for (int i = 0; i < 8; i++) xr[i] = xg[tid + 256 * i];

        float invn_[8];
#pragma unroll
        for (int i = 0; i < 8; i++) {
            float4 v = xr[i], s = swr[i];
            v.x *= s.x; v.y *= s.y; v.z *= s.z; v.w *= s.w;
            xr[i] = v;
            float ss = v.x * v.x + v.y * v.y + v.z * v.z + v.w * v.w;
#pragma unroll
            for (int d = 1; d < 32; d <<= 1) ss += __shfl_xor(ss, d);
            float nv = sqrtf(ss) + 1e-8f;
            invn_[i] = 1.0f / nv;
            if ((tid & 31) == 0) nrm[(tid >> 5) + 8 * i] = nv;
        }
        // split + write planes: row c=(tid>>5)+8i, f = 4*(tid&31)
#pragma unroll
        for (int i = 0; i < 8; i++) {
            int c = (tid >> 5) + 8 * i;
            float4 v = xr[i];
            float iv = invn_[i];
            float a0 = v.x * iv, a1 = v.y * iv, a2 = v.z * iv, a3 = v.w * iv;
            union { unsigned short u[4]; unsigned long long q; } Hq, Lq;
            unsigned short h0 = f2bf(a0), h1 = f2bf(a1), h2 = f2bf(a2), h3 = f2bf(a3);
            Hq.u[0] = h0; Hq.u[1] = h1; Hq.u[2] = h2; Hq.u[3] = h3;
            Lq.u[0] = f2bf(a0 - bf2f(h0));
            Lq.u[1] = f2bf(a1 - bf2f(h1));
            Lq.u[2] = f2bf(a2 - bf2f(h2));
            Lq.u[3] = f2bf(a3 - bf2f(h3));
            int off = c * PSTR + 4 * (tid & 31);
            *(unsigned long long*)&hhi[off] = Hq.q;
            *(unsigned long long*)&hlo[off] = Lq.q;
        }
        __syncthreads();  // (b) planes ready

        f4acc accW0 = (f4acc){0.f, 0.f, 0.f, 0.f};
        f4acc accW1 = (f4acc){0.f, 0.f, 0.f, 0.f};
#pragma unroll
        for (int k = 0; k < 4; k++) {
            const int ko = 32 * k + 8 * quad;
            bfrag r0h = *(const bfrag*)&hhi[(rt0 * 16 + l16) * PSTR + ko];
            bfrag r0l = *(const bfrag*)&hlo[(rt0 * 16 + l16) * PSTR + ko];
            bfrag r1h = *(const bfrag*)&hhi[((rt0 + 1) * 16 + l16) * PSTR + ko];
            bfrag r1l = *(const bfrag*)&hlo[((rt0 + 1) * 16 + l16) * PSTR + ko];
            bfrag c0h = *(const bfrag*)&hhi[(ct0 * 16 + l16) * PSTR + ko];
            bfrag c0l = *(const bfrag*)&hlo[(ct0 * 16 + l16) * PSTR + ko];
            bfrag c1h = *(const bfrag*)&hhi[((ct0 + 1) * 16 + l16) * PSTR + ko];
            bfrag c1l = *(const bfrag*)&hlo[((ct0 + 1) * 16 + l16) * PSTR + ko];
            // A quadrant: 4 tiles x 3 products
            accA[0][0] = MFMA16(r0h, c0h, accA[0][0]);
            accA[0][0] = MFMA16(r0h, c0l, accA[0][0]);
            accA[0][0] = MFMA16(r0l, c0h, accA[0][0]);
            accA[0][1] = MFMA16(r0h, c1h, accA[0][1]);
            accA[0][1] = MFMA16(r0h, c1l, accA[0][1]);
            accA[0][1] = MFMA16(r0l, c1h, accA[0][1]);
            accA[1][0] = MFMA16(r1h, c0h, accA[1][0]);
            accA[1][0] = MFMA16(r1h, c0l, accA[1][0]);
            accA[1][0] = MFMA16(r1l, c0h, accA[1][0]);
            accA[1][1] = MFMA16(r1h, c1h, accA[1][1]);
            accA[1][1] = MFMA16(r1h, c1l, accA[1][1]);
            accA[1][1] = MFMA16(r1l, c1h, accA[1][1]);
            // Wh tiles (rows rt0, rt0+1; col jW), W frags in regs
            accW0 = MFMA16(r0h, wfh[k], accW0);
            accW0 = MFMA16(r0h, wfl[k], accW0);
            accW0 = MFMA16(r0l, wfh[k], accW0);
            accW1 = MFMA16(r1h, wfh[k], accW1);
            accW1 = MFMA16(r1h, wfl[k], accW1);
            accW1 = MFMA16(r1l, wfh[k], accW1);
        }
        // epilogue: scale rows by nrm, write Wh, reduce s1/s2 per row
        float* whout = Wh + (size_t)(b * T_ + t) * (C_ * O_);
#pragma unroll
        for (int i2 = 0; i2 < 2; i2++) {
            f4acc aw = i2 ? accW1 : accW0;
#pragma unroll
            for (int r = 0; r < 4; r++) {
                int row = (rt0 + i2) * 16 + quad * 4 + r;
                float val = aw[r] * nrm[row];
                whout[row * O_ + l16 + 16 * jW] = val;
                float v1 = val * ga1, v2 = val * ga2;
#pragma unroll
                for (int d = 1; d < 16; d <<= 1) {
                    v1 += __shfl_xor(v1, d);
                    v2 += __shfl_xor(v2, d);
                }
                if (l16 == 0) { s1p[jW][row] = v1; s2p[jW][row] = v2; }
            }
        }
        __syncthreads();  // (c) s1p/s2p ready; also: this-t frag reads done
        if (tid < 64) {
            s1[(b * T_ + t) * C_ + tid] = s1p[0][tid] + s1p[1][tid];
            s2[(b * T_ + t) * C_ + tid] = s2p[0][tid] + s2p[1][tid];
        }
    }
    // block-end: quadrants disjoint -> direct atomicAdd
#pragma unroll
    for (int i2 = 0; i2 < 2; i2++)
#pragma unroll
        for (int j2 = 0; j2 < 2; j2++)
#pragma unroll
            for (int r = 0; r < 4; r++) {
                int row = (rt0 + i2) * 16 + quad * 4 + r;
                int col = (ct0 + j2) * 16 + l16;
                atomicAdd(&A[b * (C_ * C_) + row * C_ + col], accA[i2][j2][r]);
            }
}

// ---------------------------------------------------------------------------
// K2: top-4 selection + symmetrize -> amask bitmask per (b,c). grid B, block 64
// ---------------------------------------------------------------------------
__global__ __launch_bounds__(64) void k_topk(const float* __restrict__ A,
                                             unsigned long long* __restrict__ amask) {
    int b = blockIdx.x;
    int c = threadIdx.x;
    __shared__ unsigned long long tk[C_];
    const float* row = A + b * (C_ * C_) + c * C_;
    unsigned long long sel = 0ULL;
    for (int r = 0; r < 4; r++) {
        float best = -1e30f;
        int bi = 0;
        for (int d = 0; d < C_; d++) {
            if (sel & (1ULL << d)) continue;
            float v = row[d];
            if (v > best) { best = v; bi = d; }
        }
        sel |= (1ULL << bi);
    }
    unsigned long long t = sel & ~(1ULL << c);
    tk[c] = t;
    __syncthreads();
    unsigned long long sym = t;
    for (int d = 0; d < C_; d++)
        if ((tk[d] >> c) & 1ULL) sym |= (1ULL << d);
    unsigned long long m = (1ULL << c);
    unsigned long long s2 = sym;
    while (s2) {
        int d = __ffsll(s2) - 1;
        s2 &= s2 - 1;
        if (row[d] > 0.f) m |= (1ULL << d);
    }
    amask[b * C_ + c] = m;
}

// ---------------------------------------------------------------------------
// K3: GAT attention + relu + pooling + FUSED lstm input projection.
// block 256 = 4 waves = 4 t's. grid B*T/4.
// gx is written GATE-COLUMN-MAJOR: gxT[dir][b][col][t] (t contiguous), and
// for dir=1 already TIME-REVERSED (written at 255-t), so k_lstm_seq reads
// forward contiguous float4s regardless of direction. Per-gate accumulation
// order unchanged -> bitwise-identical values.
// ---------------------------------------------------------------------------
__global__ __launch_bounds__(256) void k_gat(
    const float* __restrict__ Wh, const float* __restrict__ s1,
    const float* __restrict__ s2, const unsigned long long* __restrict__ amask,
    const float* __restrict__ pool_w, const float* __restrict__ pool_b,
    const float* __restrict__ Wi_f, const float* __restrict__ b_f,
    const float* __restrict__ Wi_r, const float* __restrict__ b_r,
    float* __restrict__ gx) {
    int tg = blockIdx.x;
    int wv = threadIdx.x >> 6, c = threadIdx.x & 63;
    int bt = tg * 4 + wv;
    int b = bt >> 8;
    __shared__ float buf[4][C_][33];
    __shared__ float s2s[4][C_];
    __shared__ float hp[4][H_];

    s2s[wv][c] = s2[bt * C_ + c];
    float s1c = s1[bt * C_ + c];
    unsigned long long m = amask[b * C_ + c];
    __syncthreads();

    float mx = -1e30f;
    unsigned long long mm = m;
    while (mm) {
        int d = __ffsll(mm) - 1; mm &= mm - 1;
        float v = s1c + s2s[wv][d];
        v = v > 0.f ? v : 0.2f * v;
        mx = fmaxf(mx, v);
    }
    float ssum = 0.f;
    mm = m;
    while (mm) {
        int d = __ffsll(mm) - 1; mm &= mm - 1;
        float v = s1c + s2s[wv][d];
        v = v > 0.f ? v : 0.2f * v;
        ssum += __expf(v - mx);
    }
    float inv = 1.0f / ssum;
    float g[O_];
#pragma unroll
    for (int i = 0; i < O_; i++) g[i] = 0.f;
    mm = m;
    while (mm) {
        int d = __ffsll(mm) - 1; mm &= mm - 1;
        float v = s1c + s2s[wv][d];
        v = v > 0.f ? v : 0.2f * v;
        float a = __expf(v - mx);
        const float4* wr = (const float4*)(Wh + (size_t)bt * (C_ * O_) + d * O_);
#pragma unroll
        for (int q = 0; q < 8; q++) {
            float4 w4 = wr[q];
            g[4 * q + 0] += a * w4.x;
            g[4 * q + 1] += a * w4.y;
            g[4 * q + 2] += a * w4.z;
            g[4 * q + 3] += a * w4.w;
        }
    }
    float lg = pool_b[0];
#pragma unroll
    for (int i = 0; i < O_; i++) {
        g[i] = fmaxf(g[i] * inv, 0.f);
        lg += g[i] * pool_w[i];
    }
    float wmx = lg;
#pragma unroll
    for (int s = 1; s < 64; s <<= 1) wmx = fmaxf(wmx, __shfl_xor(wmx, s));
    float we = __expf(lg - wmx);
    float wsum = we;
#pragma unroll
    for (int s = 1; s < 64; s <<= 1) wsum += __shfl_xor(wsum, s);
    float wcf = we / wsum;
#pragma unroll
    for (int i = 0; i < O_; i++) buf[wv][c][i] = g[i] * wcf;
    __syncthreads();
    {
        int wt = threadIdx.x >> 6, o = threadIdx.x & 31, hf = (threadIdx.x >> 5) & 1;
        float sacc = 0.f;
#pragma unroll 8
        for (int d = hf * 32; d < hf * 32 + 32; d++) sacc += buf[wt][d][o];
        sacc += __shfl_xor(sacc, 32);
        if (hf == 0) hp[wt][o] = sacc;
    }
    __syncthreads();
    // fused lstm_pre: thread = (dir = tid>>7, col = tid&127)
    {
        int dir = threadIdx.x >> 7, col = threadIdx.x & 127;
        const float* Wi = dir ? Wi_r : Wi_f;
        const float* bb = dir ? b_r : b_f;
        float bv = bb[col];
        float a0 = bv, a1 = bv, a2 = bv, a3 = bv;
#pragma unroll
        for (int k = 0; k < H_; k++) {
            float wvv = Wi[k * G4_ + col];
            a0 = fmaf(hp[0][k], wvv, a0);
            a1 = fmaf(hp[1][k], wvv, a1);
            a2 = fmaf(hp[2][k], wvv, a2);
            a3 = fmaf(hp[3][k], wvv, a3);
        }
        int b0 = (tg * 4) >> 8;
        int t0 = (tg * 4) & 255;
        float* cb = gx + ((size_t)(dir * B_ + b0) * G4_ + col) * T_;
        if (dir == 0) {
            *(float4*)(cb + t0) = make_float4(a0, a1, a2, a3);
        } else {
            *(float4*)(cb + (252 - t0)) = make_float4(a3, a2, a1, a0);
        }
    }
}

// ---------------------------------------------------------------------------
// K4b: LSTM recurrence — LANE-SPLIT dual direction. grid B_, block 64.
// Round-5 lesson: register-doubling the dual merge made RA shuffle weights
// through AGPR/scratch (VGPR_Count stuck at 132, dur 180us). This version
// gets both chains per wave with the SAME 128 weight VGPRs: lanes 0-31 each
// own one FWD hidden unit (all 4 gates), lanes 32-63 own the REV units.
// Per-lane register contents differ (Whf vs Whr columns) but the register
// COUNT doesn't change. The c/h update is now lane-local -- the two
// critical-path ds_bpermute shfls (sf/so) are GONE; the only cross-lane op
// is the h-broadcast (32 bpermutes on the DS pipe, overlapping the FMA
// accumulation). gx column-major+pre-reversed layout matches: each lane
// reads its 4 gate columns contiguously in t; 8-step burst double-buffer.
// ---------------------------------------------------------------------------
#define KS(k) { float hk = __shfl(h, brd + k); \
    ai = fmaf(hk, wi[k], ai); af = fmaf(hk, wf[k], af); \
    ag = fmaf(hk, wg[k], ag); ao = fmaf(hk, wo[k], ao); }

#define STEPL(GI, GF, GG, GO) { \
    float ai = GI, af = GF, ag = GG, ao = GO; \
    KS(0)  KS(1)  KS(2)  KS(3)  KS(4)  KS(5)  KS(6)  KS(7) \
    KS(8)  KS(9)  KS(10) KS(11) KS(12) KS(13) KS(14) KS(15) \
    KS(16) KS(17) KS(18) KS(19) KS(20) KS(21) KS(22) KS(23) \
    KS(24) KS(25) KS(26) KS(27) KS(28) KS(29) KS(30) KS(31) \
    float sI = sigm_f(ai); \
    float sF = sigm_f(af); \
    float sG = tanh_f(ag); \
    float sO = sigm_f(ao); \
    cst = fmaf(sF, cst, sI * sG); \
    float hn = sO * tanh_f(cst); \
    h = hn; \
    *hc = hn; hc += hstride; \
}

__global__ void __attribute__((amdgpu_flat_work_group_size(64, 64)))
__attribute__((amdgpu_waves_per_eu(1, 1))) k_lstm_seq(
    const float* __restrict__ gx,
    const float* __restrict__ Whf, const float* __restrict__ Whr,
    float* __restrict__ hcat) {
    int b = blockIdx.x;
    int lane = threadIdx.x;
    int j = lane & 31;
    const int brd = lane & 32;          // broadcast group base for __shfl
    const float* Wsel = (lane < 32) ? Whf : Whr;

    // 128 weights/lane: gate columns (i,f,g,o) of this lane's hidden unit
    float wi[32], wf[32], wg[32], wo[32];
#pragma unroll
    for (int k = 0; k < 32; k++) {
        wi[k] = Wsel[k * G4_ + j];
        wf[k] = Wsel[k * G4_ + 32 + j];
        wg[k] = Wsel[k * G4_ + 64 + j];
        wo[k] = Wsel[k * G4_ + 96 + j];
    }

    // gx columns for this lane's 4 gates (column-major, rev pre-reversed)
    const int dblk = (lane < 32) ? b : (B_ + b);
    const float* pi = gx + ((size_t)dblk * G4_ + 0  + j) * T_;
    const float* pf = gx + ((size_t)dblk * G4_ + 32 + j) * T_;
    const float* pg = gx + ((size_t)dblk * G4_ + 64 + j) * T_;
    const float* po = gx + ((size_t)dblk * G4_ + 96 + j) * T_;

    // output pointer: fwd lanes walk t forward at offset j; rev lanes walk
    // t backward at offset 32+j (chain step s corresponds to t=255-s).
    float* hc = (lane < 32)
        ? (hcat + (size_t)(b * T_) * 64 + j)
        : (hcat + ((size_t)(b * T_) + T_ - 1) * 64 + 32 + j);
    const int hstride = (lane < 32) ? 64 : -64;

    float h = 0.f, cst = 0.f;

    // burst 0
    float4 ia = *(const float4*)(pi + 0), ib = *(const float4*)(pi + 4);
    float4 fa = *(const float4*)(pf + 0), fb = *(const float4*)(pf + 4);
    float4 ga = *(const float4*)(pg + 0), gb = *(const float4*)(pg + 4);
    float4 oa = *(const float4*)(po + 0), ob = *(const float4*)(po + 4);

    for (int bi = 0; bi < 32; bi++) {
        // next-burst loads (wrap on last iter: harmless, branch-free)
        int o = (8 * (bi + 1)) & 255;
        float4 nia = *(const float4*)(pi + o), nib = *(const float4*)(pi + o + 4);
        float4 nfa = *(const float4*)(pf + o), nfb = *(const float4*)(pf + o + 4);
        float4 nga = *(const float4*)(pg + o), ngb = *(const float4*)(pg + o + 4);
        float4 noa = *(const float4*)(po + o), nob = *(const float4*)(po + o + 4);

        STEPL(ia.x, fa.x, ga.x, oa.x)
        STEPL(ia.y, fa.y, ga.y, oa.y)
        STEPL(ia.z, fa.z, ga.z, oa.z)
        STEPL(ia.w, fa.w, ga.w, oa.w)
        STEPL(ib.x, fb.x, gb.x, ob.x)
        STEPL(ib.y, fb.y, gb.y, ob.y)
        STEPL(ib.z, fb.z, gb.z, ob.z)
        STEPL(ib.w, fb.w, gb.w, ob.w)

        ia = nia; ib = nib; fa = nfa; fb = nfb;
        ga = nga; gb = ngb; oa = noa; ob = nob;
    }
}

// ---------------------------------------------------------------------------
// K5: temporal attention + LN + fc1 + fc2 -> out (B,3). grid B, block 256.
// ---------------------------------------------------------------------------
__global__ __launch_bounds__(256) void k_final(
    const float* __restrict__ hcat,
    const float* __restrict__ taW, const float* __restrict__ tab,
    const float* __restrict__ tav,
    const float* __restrict__ lng, const float* __restrict__ lnb,
    const float* __restrict__ w1, const float* __restrict__ b1,
    const float* __restrict__ w2, const float* __restrict__ b2,
    float* __restrict__ out) {
    int b = blockIdx.x;
    int t = threadIdx.x;
    __shared__ float Wl[64 * 64];
    __shared__ float al[T_];
    __shared__ float wred[4];
    __shared__ float ctxp[4][64];
    __shared__ float ctx[64];
    __shared__ float a1[32];
    for (int i = t; i < 4096; i += 256) Wl[i] = taW[i];
    float4 hr[16];
    const float4* hb = (const float4*)(hcat + ((size_t)b * T_ + t) * 64);
#pragma unroll
    for (int i = 0; i < 16; i++) hr[i] = hb[i];
    __syncthreads();
    float sc = 0.f;
    for (int j = 0; j < 64; j++) {
        float s = tab[j];
#pragma unroll
        for (int k4 = 0; k4 < 16; k4++) {
            float4 h4 = hr[k4];
            const float* wcol = &Wl[(4 * k4) * 64 + j];
            s += h4.x * wcol[0] + h4.y * wcol[64] + h4.z * wcol[128] + h4.w * wcol[192];
        }
        sc += tanhf(s) * tav[j];
    }
    sc *= (1.0f / 1.5f);
    int wave = t >> 6, lane = t & 63;
    float m = sc;
#pragma unroll
    for (int s_ = 1; s_ < 64; s_ <<= 1) m = fmaxf(m, __shfl_xor(m, s_));
    if (lane == 0) wred[wave] = m;
    __syncthreads();
    m = fmaxf(fmaxf(wred[0], wred[1]), fmaxf(wred[2], wred[3]));
    float e = __expf(sc - m);
    float ssum = e;
#pragma unroll
    for (int s_ = 1; s_ < 64; s_ <<= 1) ssum += __shfl_xor(ssum, s_);
    __syncthreads();
    if (lane == 0) wred[wave] = ssum;
    __syncthreads();
    float S = wred[0] + wred[1] + wred[2] + wred[3];
    al[t] = e / S;
    __syncthreads();
    // ctx partials: thread = (part = t>>6, o = t&63)
    {
        int o = t & 63, part = t >> 6;
        float cacc = 0.f;
        for (int tt = part * 64; tt < part * 64 + 64; tt++)
            cacc += al[tt] * hcat[((size_t)b * T_ + tt) * 64 + o];
        ctxp[part][o] = cacc;
    }
    __syncthreads();
    if (t < 64) {
        float ctxo = ctxp[0][t] + ctxp[1][t] + ctxp[2][t] + ctxp[3][t];
        float sv = ctxo, sq = ctxo * ctxo;
#pragma unroll
        for (int s_ = 1; s_ < 64; s_ <<= 1) {
            sv += __shfl_xor(sv, s_);
            sq += __shfl_xor(sq, s_);
        }
        float mu = sv * (1.f / 64.f);
        float var = sq * (1.f / 64.f) - mu * mu;
        ctx[t] = (ctxo - mu) / sqrtf(var + 1e-5f) * lng[t] + lnb[t];
    }
    __syncthreads();
    if (t < 32) {
        float s = b1[t];
        for (int k = 0; k < 64; k++) s += ctx[k] * w1[k * 32 + t];
        a1[t] = fmaxf(s, 0.f);
    }
    __syncthreads();
    if (t < 3) {
        float s = b2[t];
        for (int k = 0; k < 32; k++) s += a1[k] * w2[k * 3 + t];
        out[b * 3 + t] = s;
    }
}

// ---------------------------------------------------------------------------
extern "C" void kernel_launch(void* const* d_in, const int* in_sizes, int n_in,
                              void* d_out, int out_size, void* d_ws, size_t ws_size,
                              hipStream_t stream) {
    const float* x          = (const float*)d_in[0];
    const float* spectral_w = (const float*)d_in[1];
    const float* gat_W      = (const float*)d_in[2];
    const float* gat_a      = (const float*)d_in[3];
    const float* pool_w     = (const float*)d_in[4];
    const float* pool_b     = (const float*)d_in[5];
    const float* lstm_Wi_f  = (const float*)d_in[6];
    const float* lstm_Wh_f  = (const float*)d_in[7];
    const float* lstm_b_f   = (const float*)d_in[8];
    const float* lstm_Wi_r  = (const float*)d_in[9];
    const float* lstm_Wh_r  = (const float*)d_in[10];
    const float* lstm_b_r   = (const float*)d_in[11];
    const float* ta_W       = (const float*)d_in[12];
    const float* ta_b       = (const float*)d_in[13];
    const float* ta_v       = (const float*)d_in[14];
    const float* ln_g       = (const float*)d_in[15];
    const float* ln_b       = (const float*)d_in[16];
    const float* fc1_w      = (const float*)d_in[17];
    const float* fc1_b      = (const float*)d_in[18];
    const float* fc2_w      = (const float*)d_in[19];
    const float* fc2_b      = (const float*)d_in[20];
    float* out = (float*)d_out;

    float* ws = (float*)d_ws;
    float* sw    = ws + 0;                         // 8192
    float* A     = ws + 8192;                      // 65536
    unsigned long long* amask = (unsigned long long*)(ws + 73728);  // 1024 u64
    float* Wh    = ws + 75776;                     // 8388608
    float* s1    = ws + 8464384;                   // 262144
    float* s2    = ws + 8726528;                   // 262144
    float* gx    = ws + 9119744;                   // 1048576 (column-major gxT)
    float* hcat  = ws + 10168320;                  // 262144

    hipMemsetAsync(A, 0, (size_t)C_ * C_ * B_ * sizeof(float), stream);
    k_sw<<<C_, 64, 0, stream>>>(spectral_w, sw);
    k_phase1<<<dim3(B_, T_ / TCP), 256, 0, stream>>>(x, sw, gat_W, gat_a, A, Wh, s1, s2);
    k_topk<<<B_, 64, 0, stream>>>(A, amask);
    k_gat<<<B_ * T_ / 4, 256, 0, stream>>>(Wh, s1, s2, amask, pool_w, pool_b,
                                           lstm_Wi_f, lstm_b_f, lstm_Wi_r, lstm_b_r, gx);
    k_lstm_seq<<<B_, 64, 0, stream>>>(gx, lstm_Wh_f, lstm_Wh_r, hcat);
    k_final<<<B_, 256, 0, stream>>>(hcat, ta_W, ta_b, ta_v, ln_g, ln_b,
                                    fc1_w, fc1_b, fc2_w, fc2_b, out);
}

// Round 8
// 463.217 us; speedup vs baseline: 1.1386x; 1.1272x over previous
//
#include <hip/hip_runtime.h>
#include <hip/hip_bf16.h>

// Dims
#define B_  16
#define T_  256
#define C_  64
#define F_  128
#define O_  32   // GO
#define H_  32
#define G4_ 128  // 4*H

typedef __attribute__((ext_vector_type(8))) short bfrag;
typedef __attribute__((ext_vector_type(4))) float f4acc;
typedef __attribute__((ext_vector_type(2))) float f2v;

__device__ __forceinline__ unsigned short f2bf(float v) {
    union { float f; unsigned u; } c; c.f = v;
    unsigned r = c.u + 0x7FFF + ((c.u >> 16) & 1);
    return (unsigned short)(r >> 16);
}
__device__ __forceinline__ float bf2f(unsigned short b) {
    union { float f; unsigned u; } c; c.u = ((unsigned)b) << 16; return c.f;
}
__device__ __forceinline__ float sigm_f(float x) {
    return __builtin_amdgcn_rcpf(1.f + __expf(-x));
}
__device__ __forceinline__ float tanh_f(float x) {
    float e = __expf(2.f * x);
    return 1.f - 2.f * __builtin_amdgcn_rcpf(e + 1.f);
}
__device__ __forceinline__ float readlane_f(float v, int l) {
    return __int_as_float(__builtin_amdgcn_readlane(__float_as_int(v), l));
}

// ---------------------------------------------------------------------------
// K0: softmax of spectral_w rows (64 rows of 128)
// ---------------------------------------------------------------------------
__global__ __launch_bounds__(64) void k_sw(const float* __restrict__ w,
                                           float* __restrict__ sw) {
    int c = blockIdx.x, lane = threadIdx.x;
    const float* row = w + c * F_;
    float v0 = row[lane], v1 = row[lane + 64];
    float m = fmaxf(v0, v1);
#pragma unroll
    for (int s = 1; s < 64; s <<= 1) m = fmaxf(m, __shfl_xor(m, s));
    float e0 = __expf(v0 - m), e1 = __expf(v1 - m);
    float s = e0 + e1;
#pragma unroll
    for (int s_ = 1; s_ < 64; s_ <<= 1) s += __shfl_xor(s, s_);
    sw[c * F_ + lane] = e0 / s;
    sw[c * F_ + lane + 64] = e1 / s;
}

// ---------------------------------------------------------------------------
// K1: MFMA phase1. split-bf16 (hi/lo) Hn planes in LDS.
// grid (B, T/TCP), block 256. TCP=2: 2048 blocks = 8 blocks/CU of work with
// 4 resident -> desynchronized blocks overlap load bursts with MFMA phases.
// ---------------------------------------------------------------------------
#define TCP 2
#define PSTR 136   // bf16 elements per row (272 B): 16B-aligned, bank-uniform

#define MFMA16(a, b, c) __builtin_amdgcn_mfma_f32_16x16x32_bf16(a, b, c, 0, 0, 0)

__global__ __launch_bounds__(256) void k_phase1(
    const float* __restrict__ x, const float* __restrict__ sw,
    const float* __restrict__ gat_W, const float* __restrict__ gat_a,
    float* __restrict__ A, float* __restrict__ Wh,
    float* __restrict__ s1, float* __restrict__ s2) {
    const int b = blockIdx.x, tc = blockIdx.y, tid = threadIdx.x;
    const int wv = tid >> 6, lane = tid & 63;
    const int quad = lane >> 4, l16 = lane & 15;

    __shared__ unsigned short hhi[64 * PSTR];
    __shared__ unsigned short hlo[64 * PSTR];
    __shared__ float nrm[64];
    __shared__ float s1p[2][64], s2p[2][64];

    // sw regs (same (c,f) slice every t)
    float4 swr[8];
    {
        const float4* sw4 = (const float4*)sw;
#pragma unroll
        for (int i = 0; i < 8; i++) swr[i] = sw4[tid + 256 * i];
    }

    const int rt0 = (wv >> 1) * 2;  // row-tile base {0,2}
    const int ct0 = (wv & 1) * 2;   // col-tile base {0,2}
    const int jW = wv & 1;          // Wh col-tile

    // W fragments (hi/lo) for this wave's jW, ksteps 0..3, held in regs
    bfrag wfh[4], wfl[4];
    {
        const int n = l16 + 16 * jW;
#pragma unroll
        for (int k = 0; k < 4; k++) {
            union { unsigned short u[8]; bfrag v; } Hu, Lu;
#pragma unroll
            for (int u = 0; u < 8; u++) {
                float v = gat_W[(32 * k + quad * 8 + u) * O_ + n];
                unsigned short hb = f2bf(v);
                Hu.u[u] = hb;
                Lu.u[u] = f2bf(v - bf2f(hb));
            }
            wfh[k] = Hu.v;
            wfl[k] = Lu.v;
        }
    }
    const float ga1 = gat_a[l16 + 16 * jW];
    const float ga2 = gat_a[O_ + l16 + 16 * jW];

    f4acc accA[2][2];
#pragma unroll
    for (int i = 0; i < 2; i++)
#pragma unroll
        for (int j = 0; j < 2; j++) accA[i][j] = (f4acc){0.f, 0.f, 0.f, 0.f};

    for (int tt = 0; tt < TCP; ++tt) {
        const int t = tc * TCP + tt;
        const float4* xg = (const float4*)(x + ((size_t)(b * T_ + t) << 13));
        float4 xr[8];
#pragma unroll
        for (int i = 0; i < 8; i++) xr[i] = xg[tid + 256 * i];

        float invn_[8];
#pragma unroll
        for (int i = 0; i < 8; i++) {
            float4 v = xr[i], s = swr[i];
            v.x *= s.x; v.y *= s.y; v.z *= s.z; v.w *= s.w;
            xr[i] = v;
            float ss = v.x * v.x + v.y * v.y + v.z * v.z + v.w * v.w;
#pragma unroll
            for (int d = 1; d < 32; d <<= 1) ss += __shfl_xor(ss, d);
            float nv = sqrtf(ss) + 1e-8f;
            invn_[i] = 1.0f / nv;
            if ((tid & 31) == 0) nrm[(tid >> 5) + 8 * i] = nv;
        }
        // split + write planes: row c=(tid>>5)+8i, f = 4*(tid&31)
#pragma unroll
        for (int i = 0; i < 8; i++) {
            int c = (tid >> 5) + 8 * i;
            float4 v = xr[i];
            float iv = invn_[i];
            float a0 = v.x * iv, a1 = v.y * iv, a2 = v.z * iv, a3 = v.w * iv;
            union { unsigned short u[4]; unsigned long long q; } Hq, Lq;
            unsigned short h0 = f2bf(a0), h1 = f2bf(a1), h2 = f2bf(a2), h3 = f2bf(a3);
            Hq.u[0] = h0; Hq.u[1] = h1; Hq.u[2] = h2; Hq.u[3] = h3;
            Lq.u[0] = f2bf(a0 - bf2f(h0));
            Lq.u[1] = f2bf(a1 - bf2f(h1));
            Lq.u[2] = f2bf(a2 - bf2f(h2));
            Lq.u[3] = f2bf(a3 - bf2f(h3));
            int off = c * PSTR + 4 * (tid & 31);
            *(unsigned long long*)&hhi[off] = Hq.q;
            *(unsigned long long*)&hlo[off] = Lq.q;
        }
        __syncthreads();  // (b) planes ready

        f4acc accW0 = (f4acc){0.f, 0.f, 0.f, 0.f};
        f4acc accW1 = (f4acc){0.f, 0.f, 0.f, 0.f};
#pragma unroll
        for (int k = 0; k < 4; k++) {
            const int ko = 32 * k + 8 * quad;
            bfrag r0h = *(const bfrag*)&hhi[(rt0 * 16 + l16) * PSTR + ko];
            bfrag r0l = *(const bfrag*)&hlo[(rt0 * 16 + l16) * PSTR + ko];
            bfrag r1h = *(const bfrag*)&hhi[((rt0 + 1) * 16 + l16) * PSTR + ko];
            bfrag r1l = *(const bfrag*)&hlo[((rt0 + 1) * 16 + l16) * PSTR + ko];
            bfrag c0h = *(const bfrag*)&hhi[(ct0 * 16 + l16) * PSTR + ko];
            bfrag c0l = *(const bfrag*)&hlo[(ct0 * 16 + l16) * PSTR + ko];
            bfrag c1h = *(const bfrag*)&hhi[((ct0 + 1) * 16 + l16) * PSTR + ko];
            bfrag c1l = *(const bfrag*)&hlo[((ct0 + 1) * 16 + l16) * PSTR + ko];
            // A quadrant: 4 tiles x 3 products
            accA[0][0] = MFMA16(r0h, c0h, accA[0][0]);
            accA[0][0] = MFMA16(r0h, c0l, accA[0][0]);
            accA[0][0] = MFMA16(r0l, c0h, accA[0][0]);
            accA[0][1] = MFMA16(r0h, c1h, accA[0][1]);
            accA[0][1] = MFMA16(r0h, c1l, accA[0][1]);
            accA[0][1] = MFMA16(r0l, c1h, accA[0][1]);
            accA[1][0] = MFMA16(r1h, c0h, accA[1][0]);
            accA[1][0] = MFMA16(r1h, c0l, accA[1][0]);
            accA[1][0] = MFMA16(r1l, c0h, accA[1][0]);
            accA[1][1] = MFMA16(r1h, c1h, accA[1][1]);
            accA[1][1] = MFMA16(r1h, c1l, accA[1][1]);
            accA[1][1] = MFMA16(r1l, c1h, accA[1][1]);
            // Wh tiles (rows rt0, rt0+1; col jW), W frags in regs
            accW0 = MFMA16(r0h, wfh[k], accW0);
            accW0 = MFMA16(r0h, wfl[k], accW0);
            accW0 = MFMA16(r0l, wfh[k], accW0);
            accW1 = MFMA16(r1h, wfh[k], accW1);
            accW1 = MFMA16(r1h, wfl[k], accW1);
            accW1 = MFMA16(r1l, wfh[k], accW1);
        }
        // epilogue: scale rows by nrm, write Wh, reduce s1/s2 per row
        float* whout = Wh + (size_t)(b * T_ + t) * (C_ * O_);
#pragma unroll
        for (int i2 = 0; i2 < 2; i2++) {
            f4acc aw = i2 ? accW1 : accW0;
#pragma unroll
            for (int r = 0; r < 4; r++) {
                int row = (rt0 + i2) * 16 + quad * 4 + r;
                float val = aw[r] * nrm[row];
                whout[row * O_ + l16 + 16 * jW] = val;
                float v1 = val * ga1, v2 = val * ga2;
#pragma unroll
                for (int d = 1; d < 16; d <<= 1) {
                    v1 += __shfl_xor(v1, d);
                    v2 += __shfl_xor(v2, d);
                }
                if (l16 == 0) { s1p[jW][row] = v1; s2p[jW][row] = v2; }
            }
        }
        __syncthreads();  // (c) s1p/s2p ready; also: this-t frag reads done
        if (tid < 64) {
            s1[(b * T_ + t) * C_ + tid] = s1p[0][tid] + s1p[1][tid];
            s2[(b * T_ + t) * C_ + tid] = s2p[0][tid] + s2p[1][tid];
        }
    }
    // block-end: quadrants disjoint -> direct atomicAdd
#pragma unroll
    for (int i2 = 0; i2 < 2; i2++)
#pragma unroll
        for (int j2 = 0; j2 < 2; j2++)
#pragma unroll
            for (int r = 0; r < 4; r++) {
                int row = (rt0 + i2) * 16 + quad * 4 + r;
                int col = (ct0 + j2) * 16 + l16;
                atomicAdd(&A[b * (C_ * C_) + row * C_ + col], accA[i2][j2][r]);
            }
}

// ---------------------------------------------------------------------------
// K2: top-4 selection + symmetrize -> amask bitmask per (b,c). grid B, block 64
// ---------------------------------------------------------------------------
__global__ __launch_bounds__(64) void k_topk(const float* __restrict__ A,
                                             unsigned long long* __restrict__ amask) {
    int b = blockIdx.x;
    int c = threadIdx.x;
    __shared__ unsigned long long tk[C_];
    const float* row = A + b * (C_ * C_) + c * C_;
    unsigned long long sel = 0ULL;
    for (int r = 0; r < 4; r++) {
        float best = -1e30f;
        int bi = 0;
        for (int d = 0; d < C_; d++) {
            if (sel & (1ULL << d)) continue;
            float v = row[d];
            if (v > best) { best = v; bi = d; }
        }
        sel |= (1ULL << bi);
    }
    unsigned long long t = sel & ~(1ULL << c);
    tk[c] = t;
    __syncthreads();
    unsigned long long sym = t;
    for (int d = 0; d < C_; d++)
        if ((tk[d] >> c) & 1ULL) sym |= (1ULL << d);
    unsigned long long m = (1ULL << c);
    unsigned long long s2 = sym;
    while (s2) {
        int d = __ffsll(s2) - 1;
        s2 &= s2 - 1;
        if (row[d] > 0.f) m |= (1ULL << d);
    }
    amask[b * C_ + c] = m;
}

// ---------------------------------------------------------------------------
// K3: GAT attention + relu + pooling + FUSED lstm input projection.
// block 256 = 4 waves = 4 t's. grid B*T/4.
// gx written ROW-major (round-2/3 layout, matches the 93us lstm variant).
// Per-gate accumulation order unchanged -> bitwise-identical values.
// ---------------------------------------------------------------------------
__global__ __launch_bounds__(256) void k_gat(
    const float* __restrict__ Wh, const float* __restrict__ s1,
    const float* __restrict__ s2, const unsigned long long* __restrict__ amask,
    const float* __restrict__ pool_w, const float* __restrict__ pool_b,
    const float* __restrict__ Wi_f, const float* __restrict__ b_f,
    const float* __restrict__ Wi_r, const float* __restrict__ b_r,
    float* __restrict__ gx) {
    int tg = blockIdx.x;
    int wv = threadIdx.x >> 6, c = threadIdx.x & 63;
    int bt = tg * 4 + wv;
    int b = bt >> 8;
    __shared__ float buf[4][C_][33];
    __shared__ float s2s[4][C_];
    __shared__ float hp[4][H_];

    s2s[wv][c] = s2[bt * C_ + c];
    float s1c = s1[bt * C_ + c];
    unsigned long long m = amask[b * C_ + c];
    __syncthreads();

    float mx = -1e30f;
    unsigned long long mm = m;
    while (mm) {
        int d = __ffsll(mm) - 1; mm &= mm - 1;
        float v = s1c + s2s[wv][d];
        v = v > 0.f ? v : 0.2f * v;
        mx = fmaxf(mx, v);
    }
    float ssum = 0.f;
    mm = m;
    while (mm) {
        int d = __ffsll(mm) - 1; mm &= mm - 1;
        float v = s1c + s2s[wv][d];
        v = v > 0.f ? v : 0.2f * v;
        ssum += __expf(v - mx);
    }
    float inv = 1.0f / ssum;
    float g[O_];
#pragma unroll
    for (int i = 0; i < O_; i++) g[i] = 0.f;
    mm = m;
    while (mm) {
        int d = __ffsll(mm) - 1; mm &= mm - 1;
        float v = s1c + s2s[wv][d];
        v = v > 0.f ? v : 0.2f * v;
        float a = __expf(v - mx);
        const float4* wr = (const float4*)(Wh + (size_t)bt * (C_ * O_) + d * O_);
#pragma unroll
        for (int q = 0; q < 8; q++) {
            float4 w4 = wr[q];
            g[4 * q + 0] += a * w4.x;
            g[4 * q + 1] += a * w4.y;
            g[4 * q + 2] += a * w4.z;
            g[4 * q + 3] += a * w4.w;
        }
    }
    float lg = pool_b[0];
#pragma unroll
    for (int i = 0; i < O_; i++) {
        g[i] = fmaxf(g[i] * inv, 0.f);
        lg += g[i] * pool_w[i];
    }
    float wmx = lg;
#pragma unroll
    for (int s = 1; s < 64; s <<= 1) wmx = fmaxf(wmx, __shfl_xor(wmx, s));
    float we = __expf(lg - wmx);
    float wsum = we;
#pragma unroll
    for (int s = 1; s < 64; s <<= 1) wsum += __shfl_xor(wsum, s);
    float wcf = we / wsum;
#pragma unroll
    for (int i = 0; i < O_; i++) buf[wv][c][i] = g[i] * wcf;
    __syncthreads();
    {
        int wt = threadIdx.x >> 6, o = threadIdx.x & 31, hf = (threadIdx.x >> 5) & 1;
        float sacc = 0.f;
#pragma unroll 8
        for (int d = hf * 32; d < hf * 32 + 32; d++) sacc += buf[wt][d][o];
        sacc += __shfl_xor(sacc, 32);
        if (hf == 0) hp[wt][o] = sacc;
    }
    __syncthreads();
    // fused lstm_pre: thread = (dir = tid>>7, col = tid&127), row-major gx
    {
        int dir = threadIdx.x >> 7, col = threadIdx.x & 127;
        const float* Wi = dir ? Wi_r : Wi_f;
        const float* bb = dir ? b_r : b_f;
        float bv = bb[col];
        float a0 = bv, a1 = bv, a2 = bv, a3 = bv;
#pragma unroll
        for (int k = 0; k < H_; k++) {
            float wvv = Wi[k * G4_ + col];
            a0 = fmaf(hp[0][k], wvv, a0);
            a1 = fmaf(hp[1][k], wvv, a1);
            a2 = fmaf(hp[2][k], wvv, a2);
            a3 = fmaf(hp[3][k], wvv, a3);
        }
        size_t base = (size_t)dir * 4096 + (size_t)tg * 4;
        gx[(base + 0) * G4_ + col] = a0;
        gx[(base + 1) * G4_ + col] = a1;
        gx[(base + 2) * G4_ + col] = a2;
        gx[(base + 3) * G4_ + col] = a3;
    }
}

// ---------------------------------------------------------------------------
// K4b: LSTM recurrence — single wave per (dir,b). grid 2*B, block 64.
// = round-2 known-good structure (93us) + PACKED fp32 FMA.
// Evidence ladder r2-r6: step time tracks instruction count (~5cy/instr lone
// wave), not load latency, not register capacity, not chains/wave. So: cut
// instructions. The 2 gate-column FMAs per k share the multiplier hk ->
// v_pk_fma_f32 (VOP3P). float2 ext-vector + __builtin_elementwise_fma with an
// explicit {hk,hk} splat lowers to pk_fma; per-component math is bitwise
// identical fma -> results match round-2 exactly. If clang scalarizes we land
// exactly back at round-2 (no-regression fallback).
// amdgpu_waves_per_eu(1,1): full VGPR budget for the 64 weight float2s.
// (Round-7 bench was an infra failure -- container died twice -- so this is
// the same hypothesis resubmitted with the scalar->vector cast made explicit.)
// ---------------------------------------------------------------------------
#define WW(k) f2v ww##k = (f2v){Wd[(k) * G4_ + lane], Wd[(k) * G4_ + lane + 64]};
#define KST(k, Aq) { float hk = readlane_f(h, k); \
    f2v hkv = (f2v){hk, hk}; \
    Aq = __builtin_elementwise_fma(hkv, ww##k, Aq); }

__global__ void __attribute__((amdgpu_flat_work_group_size(64, 64)))
__attribute__((amdgpu_waves_per_eu(1, 1))) k_lstm_seq(
    const float* __restrict__ gx,
    const float* __restrict__ Whf, const float* __restrict__ Whr,
    float* __restrict__ hcat) {
    int dir = blockIdx.x & 1, b = blockIdx.x >> 1;
    int lane = threadIdx.x;
    const float* Wd = dir ? Whr : Whf;
    WW(0) WW(1) WW(2) WW(3) WW(4) WW(5) WW(6) WW(7)
    WW(8) WW(9) WW(10) WW(11) WW(12) WW(13) WW(14) WW(15)
    WW(16) WW(17) WW(18) WW(19) WW(20) WW(21) WW(22) WW(23)
    WW(24) WW(25) WW(26) WW(27) WW(28) WW(29) WW(30) WW(31)

    const float* gxb = gx + ((size_t)dir * 4096 + b * T_) * G4_;
    float h = 0.f, cst = 0.f;
    const int dt = dir ? -1 : 1;
    int t = dir ? (T_ - 1) : 0;
    float g0n = gxb[t * G4_ + lane], g1n = gxb[t * G4_ + lane + 64];
    const float half_sel = (lane < 32) ? 2.f : 1.f;
    for (int s = 0; s < T_; s++) {
        int tn = t + dt;
        f2v A0 = (f2v){g0n, g1n};
        f2v A1 = (f2v){0.f, 0.f};
        f2v A2 = (f2v){0.f, 0.f};
        f2v A3 = (f2v){0.f, 0.f};
        if (s < T_ - 1) {
            g0n = gxb[tn * G4_ + lane];
            g1n = gxb[tn * G4_ + lane + 64];
        }
        KST(0, A0)  KST(1, A1)  KST(2, A2)  KST(3, A3)
        KST(4, A0)  KST(5, A1)  KST(6, A2)  KST(7, A3)
        KST(8, A0)  KST(9, A1)  KST(10, A2) KST(11, A3)
        KST(12, A0) KST(13, A1) KST(14, A2) KST(15, A3)
        KST(16, A0) KST(17, A1) KST(18, A2) KST(19, A3)
        KST(20, A0) KST(21, A1) KST(22, A2) KST(23, A3)
        KST(24, A0) KST(25, A1) KST(26, A2) KST(27, A3)
        KST(28, A0) KST(29, A1) KST(30, A2) KST(31, A3)
        f2v S01 = A0 + A1;
        f2v S23 = A2 + A3;
        f2v S = S01 + S23;
        float g0 = S.x;
        float g1 = S.y;
        // lanes<32: sA=sigm(i), sB=tanh(g)=2*sigm(2g)-1 ; lanes>=32: sA=sigm(f), sB=sigm(o)
        float sA = sigm_f(g0);
        float u = sigm_f(half_sel * g1);
        float sB = (lane < 32) ? fmaf(2.f, u, -1.f) : u;
        float sf = __shfl(sA, (lane & 31) + 32);
        float so = __shfl(sB, (lane & 31) + 32);
        cst = fmaf(sf, cst, sA * sB);
        float hn = so * tanh_f(cst);
        h = hn;
        if (lane < H_) hcat[((size_t)(b * T_) + t) * (2 * H_) + dir * H_ + lane] = hn;
        t = tn;
    }
}

// ---------------------------------------------------------------------------
// K5: temporal attention + LN + fc1 + fc2 -> out (B,3). grid B, block 256.
// ---------------------------------------------------------------------------
__global__ __launch_bounds__(256) void k_final(
    const float* __restrict__ hcat,
    const float* __restrict__ taW, const float* __restrict__ tab,
    const float* __restrict__ tav,
    const float* __restrict__ lng, const float* __restrict__ lnb,
    const float* __restrict__ w1, const float* __restrict__ b1,
    const float* __restrict__ w2, const float* __restrict__ b2,
    float* __restrict__ out) {
    int b = blockIdx.x;
    int t = threadIdx.x;
    __shared__ float Wl[64 * 64];
    __shared__ float al[T_];
    __shared__ float wred[4];
    __shared__ float ctxp[4][64];
    __shared__ float ctx[64];
    __shared__ float a1[32];
    for (int i = t; i < 4096; i += 256) Wl[i] = taW[i];
    float4 hr[16];
    const float4* hb = (const float4*)(hcat + ((size_t)b * T_ + t) * 64);
#pragma unroll
    for (int i = 0; i < 16; i++) hr[i] = hb[i];
    __syncthreads();
    float sc = 0.f;
    for (int j = 0; j < 64; j++) {
        float s = tab[j];
#pragma unroll
        for (int k4 = 0; k4 < 16; k4++) {
            float4 h4 = hr[k4];
            const float* wcol = &Wl[(4 * k4) * 64 + j];
            s += h4.x * wcol[0] + h4.y * wcol[64] + h4.z * wcol[128] + h4.w * wcol[192];
        }
        sc += tanhf(s) * tav[j];
    }
    sc *= (1.0f / 1.5f);
    int wave = t >> 6, lane = t & 63;
    float m = sc;
#pragma unroll
    for (int s_ = 1; s_ < 64; s_ <<= 1) m = fmaxf(m, __shfl_xor(m, s_));
    if (lane == 0) wred[wave] = m;
    __syncthreads();
    m = fmaxf(fmaxf(wred[0], wred[1]), fmaxf(wred[2], wred[3]));
    float e = __expf(sc - m);
    float ssum = e;
#pragma unroll
    for (int s_ = 1; s_ < 64; s_ <<= 1) ssum += __shfl_xor(ssum, s_);
    __syncthreads();
    if (lane == 0) wred[wave] = ssum;
    __syncthreads();
    float S = wred[0] + wred[1] + wred[2] + wred[3];
    al[t] = e / S;
    __syncthreads();
    // ctx partials: thread = (part = t>>6, o = t&63)
    {
        int o = t & 63, part = t >> 6;
        float cacc = 0.f;
        for (int tt = part * 64; tt < part * 64 + 64; tt++)
            cacc += al[tt] * hcat[((size_t)b * T_ + tt) * 64 + o];
        ctxp[part][o] = cacc;
    }
    __syncthreads();
    if (t < 64) {
        float ctxo = ctxp[0][t] + ctxp[1][t] + ctxp[2][t] + ctxp[3][t];
        float sv = ctxo, sq = ctxo * ctxo;
#pragma unroll
        for (int s_ = 1; s_ < 64; s_ <<= 1) {
            sv += __shfl_xor(sv, s_);
            sq += __shfl_xor(sq, s_);
        }
        float mu = sv * (1.f / 64.f);
        float var = sq * (1.f / 64.f) - mu * mu;
        ctx[t] = (ctxo - mu) / sqrtf(var + 1e-5f) * lng[t] + lnb[t];
    }
    __syncthreads();
    if (t < 32) {
        float s = b1[t];
        for (int k = 0; k < 64; k++) s += ctx[k] * w1[k * 32 + t];
        a1[t] = fmaxf(s, 0.f);
    }
    __syncthreads();
    if (t < 3) {
        float s = b2[t];
        for (int k = 0; k < 32; k++) s += a1[k] * w2[k * 3 + t];
        out[b * 3 + t] = s;
    }
}

// ---------------------------------------------------------------------------
extern "C" void kernel_launch(void* const* d_in, const int* in_sizes, int n_in,
                              void* d_out, int out_size, void* d_ws, size_t ws_size,
                              hipStream_t stream) {
    const float* x          = (const float*)d_in[0];
    const float* spectral_w = (const float*)d_in[1];
    const float* gat_W      = (const float*)d_in[2];
    const float* gat_a      = (const float*)d_in[3];
    const float* pool_w     = (const float*)d_in[4];
    const float* pool_b     = (const float*)d_in[5];
    const float* lstm_Wi_f  = (const float*)d_in[6];
    const float* lstm_Wh_f  = (const float*)d_in[7];
    const float* lstm_b_f   = (const float*)d_in[8];
    const float* lstm_Wi_r  = (const float*)d_in[9];
    const float* lstm_Wh_r  = (const float*)d_in[10];
    const float* lstm_b_r   = (const float*)d_in[11];
    const float* ta_W       = (const float*)d_in[12];
    const float* ta_b       = (const float*)d_in[13];
    const float* ta_v       = (const float*)d_in[14];
    const float* ln_g       = (const float*)d_in[15];
    const float* ln_b       = (const float*)d_in[16];
    const float* fc1_w      = (const float*)d_in[17];
    const float* fc1_b      = (const float*)d_in[18];
    const float* fc2_w      = (const float*)d_in[19];
    const float* fc2_b      = (const float*)d_in[20];
    float* out = (float*)d_out;

    float* ws = (float*)d_ws;
    float* sw    = ws + 0;                         // 8192
    float* A     = ws + 8192;                      // 65536
    unsigned long long* amask = (unsigned long long*)(ws + 73728);  // 1024 u64
    float* Wh    = ws + 75776;                     // 8388608
    float* s1    = ws + 8464384;                   // 262144
    float* s2    = ws + 8726528;                   // 262144
    float* gx    = ws + 9119744;                   // 1048576 (row-major)
    float* hcat  = ws + 10168320;                  // 262144

    hipMemsetAsync(A, 0, (size_t)C_ * C_ * B_ * sizeof(float), stream);
    k_sw<<<C_, 64, 0, stream>>>(spectral_w, sw);
    k_phase1<<<dim3(B_, T_ / TCP), 256, 0, stream>>>(x, sw, gat_W, gat_a, A, Wh, s1, s2);
    k_topk<<<B_, 64, 0, stream>>>(A, amask);
    k_gat<<<B_ * T_ / 4, 256, 0, stream>>>(Wh, s1, s2, amask, pool_w, pool_b,
                                           lstm_Wi_f, lstm_b_f, lstm_Wi_r, lstm_b_r, gx);
    k_lstm_seq<<<2 * B_, 64, 0, stream>>>(gx, lstm_Wh_f, lstm_Wh_r, hcat);
    k_final<<<B_, 256, 0, stream>>>(hcat, ta_W, ta_b, ta_v, ln_g, ln_b,
                                    fc1_w, fc1_b, fc2_w, fc2_b, out);
}

// Round 9
// 428.693 us; speedup vs baseline: 1.2303x; 1.0805x over previous
//
#include <hip/hip_runtime.h>
#include <hip/hip_bf16.h>

// Dims
#define B_  16
#define T_  256
#define C_  64
#define F_  128
#define O_  32   // GO
#define H_  32
#define G4_ 128  // 4*H

typedef __attribute__((ext_vector_type(8))) short bfrag;
typedef __attribute__((ext_vector_type(4))) float f4acc;

__device__ __forceinline__ unsigned short f2bf(float v) {
    union { float f; unsigned u; } c; c.f = v;
    unsigned r = c.u + 0x7FFF + ((c.u >> 16) & 1);
    return (unsigned short)(r >> 16);
}
__device__ __forceinline__ float bf2f(unsigned short b) {
    union { float f; unsigned u; } c; c.u = ((unsigned)b) << 16; return c.f;
}
__device__ __forceinline__ float sigm_f(float x) {
    return __builtin_amdgcn_rcpf(1.f + __expf(-x));
}
__device__ __forceinline__ float tanh_f(float x) {
    float e = __expf(2.f * x);
    return 1.f - 2.f * __builtin_amdgcn_rcpf(e + 1.f);
}
__device__ __forceinline__ float readlane_f(float v, int l) {
    return __int_as_float(__builtin_amdgcn_readlane(__float_as_int(v), l));
}

// ---------------------------------------------------------------------------
// K0: softmax of spectral_w rows (64 rows of 128)
// ---------------------------------------------------------------------------
__global__ __launch_bounds__(64) void k_sw(const float* __restrict__ w,
                                           float* __restrict__ sw) {
    int c = blockIdx.x, lane = threadIdx.x;
    const float* row = w + c * F_;
    float v0 = row[lane], v1 = row[lane + 64];
    float m = fmaxf(v0, v1);
#pragma unroll
    for (int s = 1; s < 64; s <<= 1) m = fmaxf(m, __shfl_xor(m, s));
    float e0 = __expf(v0 - m), e1 = __expf(v1 - m);
    float s = e0 + e1;
#pragma unroll
    for (int s_ = 1; s_ < 64; s_ <<= 1) s += __shfl_xor(s, s_);
    sw[c * F_ + lane] = e0 / s;
    sw[c * F_ + lane + 64] = e1 / s;
}

// ---------------------------------------------------------------------------
// K1: MFMA phase1. split-bf16 (hi/lo) Hn planes in LDS.
// grid (B, T/TCP), block 256. TCP=2: 2048 blocks = 8 blocks/CU of work with
// 4 resident -> desynchronized blocks overlap load bursts with MFMA phases.
// ---------------------------------------------------------------------------
#define TCP 2
#define PSTR 136   // bf16 elements per row (272 B): 16B-aligned, bank-uniform

#define MFMA16(a, b, c) __builtin_amdgcn_mfma_f32_16x16x32_bf16(a, b, c, 0, 0, 0)

__global__ __launch_bounds__(256) void k_phase1(
    const float* __restrict__ x, const float* __restrict__ sw,
    const float* __restrict__ gat_W, const float* __restrict__ gat_a,
    float* __restrict__ A, float* __restrict__ Wh,
    float* __restrict__ s1, float* __restrict__ s2) {
    const int b = blockIdx.x, tc = blockIdx.y, tid = threadIdx.x;
    const int wv = tid >> 6, lane = tid & 63;
    const int quad = lane >> 4, l16 = lane & 15;

    __shared__ unsigned short hhi[64 * PSTR];
    __shared__ unsigned short hlo[64 * PSTR];
    __shared__ float nrm[64];
    __shared__ float s1p[2][64], s2p[2][64];

    // sw regs (same (c,f) slice every t)
    float4 swr[8];
    {
        const float4* sw4 = (const float4*)sw;
#pragma unroll
        for (int i = 0; i < 8; i++) swr[i] = sw4[tid + 256 * i];
    }

    const int rt0 = (wv >> 1) * 2;  // row-tile base {0,2}
    const int ct0 = (wv & 1) * 2;   // col-tile base {0,2}
    const int jW = wv & 1;          // Wh col-tile

    // W fragments (hi/lo) for this wave's jW, ksteps 0..3, held in regs
    bfrag wfh[4], wfl[4];
    {
        const int n = l16 + 16 * jW;
#pragma unroll
        for (int k = 0; k < 4; k++) {
            union { unsigned short u[8]; bfrag v; } Hu, Lu;
#pragma unroll
            for (int u = 0; u < 8; u++) {
                float v = gat_W[(32 * k + quad * 8 + u) * O_ + n];
                unsigned short hb = f2bf(v);
                Hu.u[u] = hb;
                Lu.u[u] = f2bf(v - bf2f(hb));
            }
            wfh[k] = Hu.v;
            wfl[k] = Lu.v;
        }
    }
    const float ga1 = gat_a[l16 + 16 * jW];
    const float ga2 = gat_a[O_ + l16 + 16 * jW];

    f4acc accA[2][2];
#pragma unroll
    for (int i = 0; i < 2; i++)
#pragma unroll
        for (int j = 0; j < 2; j++) accA[i][j] = (f4acc){0.f, 0.f, 0.f, 0.f};

    for (int tt = 0; tt < TCP; ++tt) {
        const int t = tc * TCP + tt;
        const float4* xg = (const float4*)(x + ((size_t)(b * T_ + t) << 13));
        float4 xr[8];
#pragma unroll
        for (int i = 0; i < 8; i++) xr[i] = xg[tid + 256 * i];

        float invn_[8];
#pragma unroll
        for (int i = 0; i < 8; i++) {
            float4 v = xr[i], s = swr[i];
            v.x *= s.x; v.y *= s.y; v.z *= s.z; v.w *= s.w;
            xr[i] = v;
            float ss = v.x * v.x + v.y * v.y + v.z * v.z + v.w * v.w;
#pragma unroll
            for (int d = 1; d < 32; d <<= 1) ss += __shfl_xor(ss, d);
            float nv = sqrtf(ss) + 1e-8f;
            invn_[i] = 1.0f / nv;
            if ((tid & 31) == 0) nrm[(tid >> 5) + 8 * i] = nv;
        }
        // split + write planes: row c=(tid>>5)+8i, f = 4*(tid&31)
#pragma unroll
        for (int i = 0; i < 8; i++) {
            int c = (tid >> 5) + 8 * i;
            float4 v = xr[i];
            float iv = invn_[i];
            float a0 = v.x * iv, a1 = v.y * iv, a2 = v.z * iv, a3 = v.w * iv;
            union { unsigned short u[4]; unsigned long long q; } Hq, Lq;
            unsigned short h0 = f2bf(a0), h1 = f2bf(a1), h2 = f2bf(a2), h3 = f2bf(a3);
            Hq.u[0] = h0; Hq.u[1] = h1; Hq.u[2] = h2; Hq.u[3] = h3;
            Lq.u[0] = f2bf(a0 - bf2f(h0));
            Lq.u[1] = f2bf(a1 - bf2f(h1));
            Lq.u[2] = f2bf(a2 - bf2f(h2));
            Lq.u[3] = f2bf(a3 - bf2f(h3));
            int off = c * PSTR + 4 * (tid & 31);
            *(unsigned long long*)&hhi[off] = Hq.q;
            *(unsigned long long*)&hlo[off] = Lq.q;
        }
        __syncthreads();  // (b) planes ready

        f4acc accW0 = (f4acc){0.f, 0.f, 0.f, 0.f};
        f4acc accW1 = (f4acc){0.f, 0.f, 0.f, 0.f};
#pragma unroll
        for (int k = 0; k < 4; k++) {
            const int ko = 32 * k + 8 * quad;
            bfrag r0h = *(const bfrag*)&hhi[(rt0 * 16 + l16) * PSTR + ko];
            bfrag r0l = *(const bfrag*)&hlo[(rt0 * 16 + l16) * PSTR + ko];
            bfrag r1h = *(const bfrag*)&hhi[((rt0 + 1) * 16 + l16) * PSTR + ko];
            bfrag r1l = *(const bfrag*)&hlo[((rt0 + 1) * 16 + l16) * PSTR + ko];
            bfrag c0h = *(const bfrag*)&hhi[(ct0 * 16 + l16) * PSTR + ko];
            bfrag c0l = *(const bfrag*)&hlo[(ct0 * 16 + l16) * PSTR + ko];
            bfrag c1h = *(const bfrag*)&hhi[((ct0 + 1) * 16 + l16) * PSTR + ko];
            bfrag c1l = *(const bfrag*)&hlo[((ct0 + 1) * 16 + l16) * PSTR + ko];
            // A quadrant: 4 tiles x 3 products
            accA[0][0] = MFMA16(r0h, c0h, accA[0][0]);
            accA[0][0] = MFMA16(r0h, c0l, accA[0][0]);
            accA[0][0] = MFMA16(r0l, c0h, accA[0][0]);
            accA[0][1] = MFMA16(r0h, c1h, accA[0][1]);
            accA[0][1] = MFMA16(r0h, c1l, accA[0][1]);
            accA[0][1] = MFMA16(r0l, c1h, accA[0][1]);
            accA[1][0] = MFMA16(r1h, c0h, accA[1][0]);
            accA[1][0] = MFMA16(r1h, c0l, accA[1][0]);
            accA[1][0] = MFMA16(r1l, c0h, accA[1][0]);
            accA[1][1] = MFMA16(r1h, c1h, accA[1][1]);
            accA[1][1] = MFMA16(r1h, c1l, accA[1][1]);
            accA[1][1] = MFMA16(r1l, c1h, accA[1][1]);
            // Wh tiles (rows rt0, rt0+1; col jW), W frags in regs
            accW0 = MFMA16(r0h, wfh[k], accW0);
            accW0 = MFMA16(r0h, wfl[k], accW0);
            accW0 = MFMA16(r0l, wfh[k], accW0);
            accW1 = MFMA16(r1h, wfh[k], accW1);
            accW1 = MFMA16(r1h, wfl[k], accW1);
            accW1 = MFMA16(r1l, wfh[k], accW1);
        }
        // epilogue: scale rows by nrm, write Wh, reduce s1/s2 per row
        float* whout = Wh + (size_t)(b * T_ + t) * (C_ * O_);
#pragma unroll
        for (int i2 = 0; i2 < 2; i2++) {
            f4acc aw = i2 ? accW1 : accW0;
#pragma unroll
            for (int r = 0; r < 4; r++) {
                int row = (rt0 + i2) * 16 + quad * 4 + r;
                float val = aw[r] * nrm[row];
                whout[row * O_ + l16 + 16 * jW] = val;
                float v1 = val * ga1, v2 = val * ga2;
#pragma unroll
                for (int d = 1; d < 16; d <<= 1) {
                    v1 += __shfl_xor(v1, d);
                    v2 += __shfl_xor(v2, d);
                }
                if (l16 == 0) { s1p[jW][row] = v1; s2p[jW][row] = v2; }
            }
        }
        __syncthreads();  // (c) s1p/s2p ready; also: this-t frag reads done
        if (tid < 64) {
            s1[(b * T_ + t) * C_ + tid] = s1p[0][tid] + s1p[1][tid];
            s2[(b * T_ + t) * C_ + tid] = s2p[0][tid] + s2p[1][tid];
        }
    }
    // block-end: quadrants disjoint -> direct atomicAdd
#pragma unroll
    for (int i2 = 0; i2 < 2; i2++)
#pragma unroll
        for (int j2 = 0; j2 < 2; j2++)
#pragma unroll
            for (int r = 0; r < 4; r++) {
                int row = (rt0 + i2) * 16 + quad * 4 + r;
                int col = (ct0 + j2) * 16 + l16;
                atomicAdd(&A[b * (C_ * C_) + row * C_ + col], accA[i2][j2][r]);
            }
}

// ---------------------------------------------------------------------------
// K2: top-4 selection + symmetrize -> amask bitmask per (b,c). grid B, block 64
// ---------------------------------------------------------------------------
__global__ __launch_bounds__(64) void k_topk(const float* __restrict__ A,
                                             unsigned long long* __restrict__ amask) {
    int b = blockIdx.x;
    int c = threadIdx.x;
    __shared__ unsigned long long tk[C_];
    const float* row = A + b * (C_ * C_) + c * C_;
    unsigned long long sel = 0ULL;
    for (int r = 0; r < 4; r++) {
        float best = -1e30f;
        int bi = 0;
        for (int d = 0; d < C_; d++) {
            if (sel & (1ULL << d)) continue;
            float v = row[d];
            if (v > best) { best = v; bi = d; }
        }
        sel |= (1ULL << bi);
    }
    unsigned long long t = sel & ~(1ULL << c);
    tk[c] = t;
    __syncthreads();
    unsigned long long sym = t;
    for (int d = 0; d < C_; d++)
        if ((tk[d] >> c) & 1ULL) sym |= (1ULL << d);
    unsigned long long m = (1ULL << c);
    unsigned long long s2 = sym;
    while (s2) {
        int d = __ffsll(s2) - 1;
        s2 &= s2 - 1;
        if (row[d] > 0.f) m |= (1ULL << d);
    }
    amask[b * C_ + c] = m;
}

// ---------------------------------------------------------------------------
// K3: GAT attention + relu + pooling + FUSED lstm input projection.
// block 256 = 4 waves = 4 t's. grid B*T/4.
// NEW: each wave stages its Wh[bt] tile (64x32 f32 = 8KB) into LDS with
// coalesced float4 loads (lane reads f4 index c+64q -> 1KB/instr), then the
// DIVERGENT mask loop reads LDS instead of re-reading global rows (~6 rows
// per (bt,c) = ~200MB of repeated L2/global reads eliminated). The staging
// buffer OVERLAYS buf: Whs is fully consumed (within-wave, lockstep) before
// the wave writes its buf slice. Stride 36 floats keeps float4 alignment;
// pooling reads are 2-way conflicts (free). FP order per output unchanged.
// ---------------------------------------------------------------------------
__global__ __launch_bounds__(256) void k_gat(
    const float* __restrict__ Wh, const float* __restrict__ s1,
    const float* __restrict__ s2, const unsigned long long* __restrict__ amask,
    const float* __restrict__ pool_w, const float* __restrict__ pool_b,
    const float* __restrict__ Wi_f, const float* __restrict__ b_f,
    const float* __restrict__ Wi_r, const float* __restrict__ b_r,
    float* __restrict__ gx) {
    int tg = blockIdx.x;
    int wv = threadIdx.x >> 6, c = threadIdx.x & 63;
    int bt = tg * 4 + wv;
    int b = bt >> 8;
    __shared__ float shm[4][C_][36];   // phase A: staged Wh[bt]; phase B: buf
    __shared__ float s2s[4][C_];
    __shared__ float hp[4][H_];

    // stage Wh[bt] -> shm[wv] (wave-local, coalesced; no block sync needed)
    {
        const float4* src = (const float4*)(Wh + (size_t)bt * (C_ * O_));
#pragma unroll
        for (int q = 0; q < 8; q++) {
            int f = c + 64 * q;            // float4 index in the 512-f4 tile
            float4 v = src[f];
            *(float4*)&shm[wv][f >> 3][4 * (f & 7)] = v;
        }
    }

    s2s[wv][c] = s2[bt * C_ + c];
    float s1c = s1[bt * C_ + c];
    unsigned long long m = amask[b * C_ + c];
    __syncthreads();

    float mx = -1e30f;
    unsigned long long mm = m;
    while (mm) {
        int d = __ffsll(mm) - 1; mm &= mm - 1;
        float v = s1c + s2s[wv][d];
        v = v > 0.f ? v : 0.2f * v;
        mx = fmaxf(mx, v);
    }
    float ssum = 0.f;
    mm = m;
    while (mm) {
        int d = __ffsll(mm) - 1; mm &= mm - 1;
        float v = s1c + s2s[wv][d];
        v = v > 0.f ? v : 0.2f * v;
        ssum += __expf(v - mx);
    }
    float inv = 1.0f / ssum;
    float g[O_];
#pragma unroll
    for (int i = 0; i < O_; i++) g[i] = 0.f;
    mm = m;
    while (mm) {
        int d = __ffsll(mm) - 1; mm &= mm - 1;
        float v = s1c + s2s[wv][d];
        v = v > 0.f ? v : 0.2f * v;
        float a = __expf(v - mx);
        const float* wr = &shm[wv][d][0];
#pragma unroll
        for (int q = 0; q < 8; q++) {
            float4 w4 = *(const float4*)&wr[4 * q];
            g[4 * q + 0] += a * w4.x;
            g[4 * q + 1] += a * w4.y;
            g[4 * q + 2] += a * w4.z;
            g[4 * q + 3] += a * w4.w;
        }
    }
    float lg = pool_b[0];
#pragma unroll
    for (int i = 0; i < O_; i++) {
        g[i] = fmaxf(g[i] * inv, 0.f);
        lg += g[i] * pool_w[i];
    }
    float wmx = lg;
#pragma unroll
    for (int s = 1; s < 64; s <<= 1) wmx = fmaxf(wmx, __shfl_xor(wmx, s));
    float we = __expf(lg - wmx);
    float wsum = we;
#pragma unroll
    for (int s = 1; s < 64; s <<= 1) wsum += __shfl_xor(wsum, s);
    float wcf = we / wsum;
    // phase B: reuse shm[wv] as buf (Whs fully consumed by this wave above)
#pragma unroll
    for (int i = 0; i < O_; i++) shm[wv][c][i] = g[i] * wcf;
    __syncthreads();
    {
        int wt = threadIdx.x >> 6, o = threadIdx.x & 31, hf = (threadIdx.x >> 5) & 1;
        float sacc = 0.f;
#pragma unroll 8
        for (int d = hf * 32; d < hf * 32 + 32; d++) sacc += shm[wt][d][o];
        sacc += __shfl_xor(sacc, 32);
        if (hf == 0) hp[wt][o] = sacc;
    }
    __syncthreads();
    // fused lstm_pre: thread = (dir = tid>>7, col = tid&127), row-major gx
    {
        int dir = threadIdx.x >> 7, col = threadIdx.x & 127;
        const float* Wi = dir ? Wi_r : Wi_f;
        const float* bb = dir ? b_r : b_f;
        float bv = bb[col];
        float a0 = bv, a1 = bv, a2 = bv, a3 = bv;
#pragma unroll
        for (int k = 0; k < H_; k++) {
            float wvv = Wi[k * G4_ + col];
            a0 = fmaf(hp[0][k], wvv, a0);
            a1 = fmaf(hp[1][k], wvv, a1);
            a2 = fmaf(hp[2][k], wvv, a2);
            a3 = fmaf(hp[3][k], wvv, a3);
        }
        size_t base = (size_t)dir * 4096 + (size_t)tg * 4;
        gx[(base + 0) * G4_ + col] = a0;
        gx[(base + 1) * G4_ + col] = a1;
        gx[(base + 2) * G4_ + col] = a2;
        gx[(base + 3) * G4_ + col] = a3;
    }
}

// ---------------------------------------------------------------------------
// K4b: LSTM recurrence — single wave per (dir,b). grid 2*B, block 64.
// ROUND-2 VERBATIM (93us, best of 6 variants tried r2-r8: rolling prefetch
// 111, burst dbuf 107, reg-doubled dual 180, lane-split dual 172, packed
// pk_fma 116 -- the pk_fma pair-alignment forced per-step v_mov packing).
// Accepted as local optimum; the kernel is issue-latency-bound at ~5cy/instr
// for a lone wave and this form has the shortest step stream.
// ---------------------------------------------------------------------------
#define WW(k) float2 ww##k = make_float2(Wd[(k) * G4_ + lane], Wd[(k) * G4_ + lane + 64]);
#define KST(k, Aq) { float hk = readlane_f(h, k); \
    Aq.x = fmaf(hk, ww##k.x, Aq.x); Aq.y = fmaf(hk, ww##k.y, Aq.y); }

__global__ void __attribute__((amdgpu_flat_work_group_size(64, 64)))
__attribute__((amdgpu_waves_per_eu(1, 1))) k_lstm_seq(
    const float* __restrict__ gx,
    const float* __restrict__ Whf, const float* __restrict__ Whr,
    float* __restrict__ hcat) {
    int dir = blockIdx.x & 1, b = blockIdx.x >> 1;
    int lane = threadIdx.x;
    const float* Wd = dir ? Whr : Whf;
    WW(0) WW(1) WW(2) WW(3) WW(4) WW(5) WW(6) WW(7)
    WW(8) WW(9) WW(10) WW(11) WW(12) WW(13) WW(14) WW(15)
    WW(16) WW(17) WW(18) WW(19) WW(20) WW(21) WW(22) WW(23)
    WW(24) WW(25) WW(26) WW(27) WW(28) WW(29) WW(30) WW(31)

    const float* gxb = gx + ((size_t)dir * 4096 + b * T_) * G4_;
    float h = 0.f, cst = 0.f;
    const int dt = dir ? -1 : 1;
    int t = dir ? (T_ - 1) : 0;
    float g0n = gxb[t * G4_ + lane], g1n = gxb[t * G4_ + lane + 64];
    const float half_sel = (lane < 32) ? 2.f : 1.f;
    for (int s = 0; s < T_; s++) {
        int tn = t + dt;
        float2 A0 = make_float2(g0n, g1n);
        float2 A1 = make_float2(0.f, 0.f);
        float2 A2 = make_float2(0.f, 0.f);
        float2 A3 = make_float2(0.f, 0.f);
        if (s < T_ - 1) {
            g0n = gxb[tn * G4_ + lane];
            g1n = gxb[tn * G4_ + lane + 64];
        }
        KST(0, A0)  KST(1, A1)  KST(2, A2)  KST(3, A3)
        KST(4, A0)  KST(5, A1)  KST(6, A2)  KST(7, A3)
        KST(8, A0)  KST(9, A1)  KST(10, A2) KST(11, A3)
        KST(12, A0) KST(13, A1) KST(14, A2) KST(15, A3)
        KST(16, A0) KST(17, A1) KST(18, A2) KST(19, A3)
        KST(20, A0) KST(21, A1) KST(22, A2) KST(23, A3)
        KST(24, A0) KST(25, A1) KST(26, A2) KST(27, A3)
        KST(28, A0) KST(29, A1) KST(30, A2) KST(31, A3)
        float g0 = (A0.x + A1.x) + (A2.x + A3.x);
        float g1 = (A0.y + A1.y) + (A2.y + A3.y);
        // lanes<32: sA=sigm(i), sB=tanh(g)=2*sigm(2g)-1 ; lanes>=32: sA=sigm(f), sB=sigm(o)
        float sA = sigm_f(g0);
        float u = sigm_f(half_sel * g1);
        float sB = (lane < 32) ? fmaf(2.f, u, -1.f) : u;
        float sf = __shfl(sA, (lane & 31) + 32);
        float so = __shfl(sB, (lane & 31) + 32);
        cst = fmaf(sf, cst, sA * sB);
        float hn = so * tanh_f(cst);
        h = hn;
        if (lane < H_) hcat[((size_t)(b * T_) + t) * (2 * H_) + dir * H_ + lane] = hn;
        t = tn;
    }
}

// ---------------------------------------------------------------------------
// K5: temporal attention + LN + fc1 + fc2 -> out (B,3). grid B, block 256.
// ---------------------------------------------------------------------------
__global__ __launch_bounds__(256) void k_final(
    const float* __restrict__ hcat,
    const float* __restrict__ taW, const float* __restrict__ tab,
    const float* __restrict__ tav,
    const float* __restrict__ lng, const float* __restrict__ lnb,
    const float* __restrict__ w1, const float* __restrict__ b1,
    const float* __restrict__ w2, const float* __restrict__ b2,
    float* __restrict__ out) {
    int b = blockIdx.x;
    int t = threadIdx.x;
    __shared__ float Wl[64 * 64];
    __shared__ float al[T_];
    __shared__ float wred[4];
    __shared__ float ctxp[4][64];
    __shared__ float ctx[64];
    __shared__ float a1[32];
    for (int i = t; i < 4096; i += 256) Wl[i] = taW[i];
    float4 hr[16];
    const float4* hb = (const float4*)(hcat + ((size_t)b * T_ + t) * 64);
#pragma unroll
    for (int i = 0; i < 16; i++) hr[i] = hb[i];
    __syncthreads();
    float sc = 0.f;
    for (int j = 0; j < 64; j++) {
        float s = tab[j];
#pragma unroll
        for (int k4 = 0; k4 < 16; k4++) {
            float4 h4 = hr[k4];
            const float* wcol = &Wl[(4 * k4) * 64 + j];
            s += h4.x * wcol[0] + h4.y * wcol[64] + h4.z * wcol[128] + h4.w * wcol[192];
        }
        sc += tanhf(s) * tav[j];
    }
    sc *= (1.0f / 1.5f);
    int wave = t >> 6, lane = t & 63;
    float m = sc;
#pragma unroll
    for (int s_ = 1; s_ < 64; s_ <<= 1) m = fmaxf(m, __shfl_xor(m, s_));
    if (lane == 0) wred[wave] = m;
    __syncthreads();
    m = fmaxf(fmaxf(wred[0], wred[1]), fmaxf(wred[2], wred[3]));
    float e = __expf(sc - m);
    float ssum = e;
#pragma unroll
    for (int s_ = 1; s_ < 64; s_ <<= 1) ssum += __shfl_xor(ssum, s_);
    __syncthreads();
    if (lane == 0) wred[wave] = ssum;
    __syncthreads();
    float S = wred[0] + wred[1] + wred[2] + wred[3];
    al[t] = e / S;
    __syncthreads();
    // ctx partials: thread = (part = t>>6, o = t&63)
    {
        int o = t & 63, part = t >> 6;
        float cacc = 0.f;
        for (int tt = part * 64; tt < part * 64 + 64; tt++)
            cacc += al[tt] * hcat[((size_t)b * T_ + tt) * 64 + o];
        ctxp[part][o] = cacc;
    }
    __syncthreads();
    if (t < 64) {
        float ctxo = ctxp[0][t] + ctxp[1][t] + ctxp[2][t] + ctxp[3][t];
        float sv = ctxo, sq = ctxo * ctxo;
#pragma unroll
        for (int s_ = 1; s_ < 64; s_ <<= 1) {
            sv += __shfl_xor(sv, s_);
            sq += __shfl_xor(sq, s_);
        }
        float mu = sv * (1.f / 64.f);
        float var = sq * (1.f / 64.f) - mu * mu;
        ctx[t] = (ctxo - mu) / sqrtf(var + 1e-5f) * lng[t] + lnb[t];
    }
    __syncthreads();
    if (t < 32) {
        float s = b1[t];
        for (int k = 0; k < 64; k++) s += ctx[k] * w1[k * 32 + t];
        a1[t] = fmaxf(s, 0.f);
    }
    __syncthreads();
    if (t < 3) {
        float s = b2[t];
        for (int k = 0; k < 32; k++) s += a1[k] * w2[k * 3 + t];
        out[b * 3 + t] = s;
    }
}

// ---------------------------------------------------------------------------
extern "C" void kernel_launch(void* const* d_in, const int* in_sizes, int n_in,
                              void* d_out, int out_size, void* d_ws, size_t ws_size,
                              hipStream_t stream) {
    const float* x          = (const float*)d_in[0];
    const float* spectral_w = (const float*)d_in[1];
    const float* gat_W      = (const float*)d_in[2];
    const float* gat_a      = (const float*)d_in[3];
    const float* pool_w     = (const float*)d_in[4];
    const float* pool_b     = (const float*)d_in[5];
    const float* lstm_Wi_f  = (const float*)d_in[6];
    const float* lstm_Wh_f  = (const float*)d_in[7];
    const float* lstm_b_f   = (const float*)d_in[8];
    const float* lstm_Wi_r  = (const float*)d_in[9];
    const float* lstm_Wh_r  = (const float*)d_in[10];
    const float* lstm_b_r   = (const float*)d_in[11];
    const float* ta_W       = (const float*)d_in[12];
    const float* ta_b       = (const float*)d_in[13];
    const float* ta_v       = (const float*)d_in[14];
    const float* ln_g       = (const float*)d_in[15];
    const float* ln_b       = (const float*)d_in[16];
    const float* fc1_w      = (const float*)d_in[17];
    const float* fc1_b      = (const float*)d_in[18];
    const float* fc2_w      = (const float*)d_in[19];
    const float* fc2_b      = (const float*)d_in[20];
    float* out = (float*)d_out;

    float* ws = (float*)d_ws;
    float* sw    = ws + 0;                         // 8192
    float* A     = ws + 8192;                      // 65536
    unsigned long long* amask = (unsigned long long*)(ws + 73728);  // 1024 u64
    float* Wh    = ws + 75776;                     // 8388608
    float* s1    = ws + 8464384;                   // 262144
    float* s2    = ws + 8726528;                   // 262144
    float* gx    = ws + 9119744;                   // 1048576 (row-major)
    float* hcat  = ws + 10168320;                  // 262144

    hipMemsetAsync(A, 0, (size_t)C_ * C_ * B_ * sizeof(float), stream);
    k_sw<<<C_, 64, 0, stream>>>(spectral_w, sw);
    k_phase1<<<dim3(B_, T_ / TCP), 256, 0, stream>>>(x, sw, gat_W, gat_a, A, Wh, s1, s2);
    k_topk<<<B_, 64, 0, stream>>>(A, amask);
    k_gat<<<B_ * T_ / 4, 256, 0, stream>>>(Wh, s1, s2, amask, pool_w, pool_b,
                                           lstm_Wi_f, lstm_b_f, lstm_Wi_r, lstm_b_r, gx);
    k_lstm_seq<<<2 * B_, 64, 0, stream>>>(gx, lstm_Wh_f, lstm_Wh_r, hcat);
    k_final<<<B_, 256, 0, stream>>>(hcat, ta_W, ta_b, ta_v, ln_g, ln_b,
                                    fc1_w, fc1_b, fc2_w, fc2_b, out);
}

// Round 10
// 406.015 us; speedup vs baseline: 1.2990x; 1.0559x over previous
//
#include <hip/hip_runtime.h>
#include <hip/hip_bf16.h>

// Dims
#define B_  16
#define T_  256
#define C_  64
#define F_  128
#define O_  32   // GO
#define H_  32
#define G4_ 128  // 4*H

typedef __attribute__((ext_vector_type(8))) short bfrag;
typedef __attribute__((ext_vector_type(4))) float f4acc;

__device__ __forceinline__ unsigned short f2bf(float v) {
    union { float f; unsigned u; } c; c.f = v;
    unsigned r = c.u + 0x7FFF + ((c.u >> 16) & 1);
    return (unsigned short)(r >> 16);
}
__device__ __forceinline__ float bf2f(unsigned short b) {
    union { float f; unsigned u; } c; c.u = ((unsigned)b) << 16; return c.f;
}
__device__ __forceinline__ float sigm_f(float x) {
    return __builtin_amdgcn_rcpf(1.f + __expf(-x));
}
__device__ __forceinline__ float tanh_f(float x) {
    float e = __expf(2.f * x);
    return 1.f - 2.f * __builtin_amdgcn_rcpf(e + 1.f);
}
__device__ __forceinline__ float readlane_f(float v, int l) {
    return __int_as_float(__builtin_amdgcn_readlane(__float_as_int(v), l));
}

// ---------------------------------------------------------------------------
// K0: softmax of spectral_w rows (64 rows of 128)
// ---------------------------------------------------------------------------
__global__ __launch_bounds__(64) void k_sw(const float* __restrict__ w,
                                           float* __restrict__ sw) {
    int c = blockIdx.x, lane = threadIdx.x;
    const float* row = w + c * F_;
    float v0 = row[lane], v1 = row[lane + 64];
    float m = fmaxf(v0, v1);
#pragma unroll
    for (int s = 1; s < 64; s <<= 1) m = fmaxf(m, __shfl_xor(m, s));
    float e0 = __expf(v0 - m), e1 = __expf(v1 - m);
    float s = e0 + e1;
#pragma unroll
    for (int s_ = 1; s_ < 64; s_ <<= 1) s += __shfl_xor(s, s_);
    sw[c * F_ + lane] = e0 / s;
    sw[c * F_ + lane + 64] = e1 / s;
}

// ---------------------------------------------------------------------------
// K1: MFMA phase1. split-bf16 (hi/lo) Hn planes in LDS.
// grid (B, T/TCP), block 256. TCP=2: 2048 blocks = 8 blocks/CU of work with
// 4 resident -> desynchronized blocks overlap load bursts with MFMA phases.
// ---------------------------------------------------------------------------
#define TCP 2
#define PSTR 136   // bf16 elements per row (272 B): 16B-aligned, bank-uniform

#define MFMA16(a, b, c) __builtin_amdgcn_mfma_f32_16x16x32_bf16(a, b, c, 0, 0, 0)

__global__ __launch_bounds__(256) void k_phase1(
    const float* __restrict__ x, const float* __restrict__ sw,
    const float* __restrict__ gat_W, const float* __restrict__ gat_a,
    float* __restrict__ A, float* __restrict__ Wh,
    float* __restrict__ s1, float* __restrict__ s2) {
    const int b = blockIdx.x, tc = blockIdx.y, tid = threadIdx.x;
    const int wv = tid >> 6, lane = tid & 63;
    const int quad = lane >> 4, l16 = lane & 15;

    __shared__ unsigned short hhi[64 * PSTR];
    __shared__ unsigned short hlo[64 * PSTR];
    __shared__ float nrm[64];
    __shared__ float s1p[2][64], s2p[2][64];

    // sw regs (same (c,f) slice every t)
    float4 swr[8];
    {
        const float4* sw4 = (const float4*)sw;
#pragma unroll
        for (int i = 0; i < 8; i++) swr[i] = sw4[tid + 256 * i];
    }

    const int rt0 = (wv >> 1) * 2;  // row-tile base {0,2}
    const int ct0 = (wv & 1) * 2;   // col-tile base {0,2}
    const int jW = wv & 1;          // Wh col-tile

    // W fragments (hi/lo) for this wave's jW, ksteps 0..3, held in regs
    bfrag wfh[4], wfl[4];
    {
        const int n = l16 + 16 * jW;
#pragma unroll
        for (int k = 0; k < 4; k++) {
            union { unsigned short u[8]; bfrag v; } Hu, Lu;
#pragma unroll
            for (int u = 0; u < 8; u++) {
                float v = gat_W[(32 * k + quad * 8 + u) * O_ + n];
                unsigned short hb = f2bf(v);
                Hu.u[u] = hb;
                Lu.u[u] = f2bf(v - bf2f(hb));
            }
            wfh[k] = Hu.v;
            wfl[k] = Lu.v;
        }
    }
    const float ga1 = gat_a[l16 + 16 * jW];
    const float ga2 = gat_a[O_ + l16 + 16 * jW];

    f4acc accA[2][2];
#pragma unroll
    for (int i = 0; i < 2; i++)
#pragma unroll
        for (int j = 0; j < 2; j++) accA[i][j] = (f4acc){0.f, 0.f, 0.f, 0.f};

    for (int tt = 0; tt < TCP; ++tt) {
        const int t = tc * TCP + tt;
        const float4* xg = (const float4*)(x + ((size_t)(b * T_ + t) << 13));
        float4 xr[8];
#pragma unroll
        for (int i = 0; i < 8; i++) xr[i] = xg[tid + 256 * i];

        float invn_[8];
#pragma unroll
        for (int i = 0; i < 8; i++) {
            float4 v = xr[i], s = swr[i];
            v.x *= s.x; v.y *= s.y; v.z *= s.z; v.w *= s.w;
            xr[i] = v;
            float ss = v.x * v.x + v.y * v.y + v.z * v.z + v.w * v.w;
#pragma unroll
            for (int d = 1; d < 32; d <<= 1) ss += __shfl_xor(ss, d);
            float nv = sqrtf(ss) + 1e-8f;
            invn_[i] = 1.0f / nv;
            if ((tid & 31) == 0) nrm[(tid >> 5) + 8 * i] = nv;
        }
        // split + write planes: row c=(tid>>5)+8i, f = 4*(tid&31)
#pragma unroll
        for (int i = 0; i < 8; i++) {
            int c = (tid >> 5) + 8 * i;
            float4 v = xr[i];
            float iv = invn_[i];
            float a0 = v.x * iv, a1 = v.y * iv, a2 = v.z * iv, a3 = v.w * iv;
            union { unsigned short u[4]; unsigned long long q; } Hq, Lq;
            unsigned short h0 = f2bf(a0), h1 = f2bf(a1), h2 = f2bf(a2), h3 = f2bf(a3);
            Hq.u[0] = h0; Hq.u[1] = h1; Hq.u[2] = h2; Hq.u[3] = h3;
            Lq.u[0] = f2bf(a0 - bf2f(h0));
            Lq.u[1] = f2bf(a1 - bf2f(h1));
            Lq.u[2] = f2bf(a2 - bf2f(h2));
            Lq.u[3] = f2bf(a3 - bf2f(h3));
            int off = c * PSTR + 4 * (tid & 31);
            *(unsigned long long*)&hhi[off] = Hq.q;
            *(unsigned long long*)&hlo[off] = Lq.q;
        }
        __syncthreads();  // (b) planes ready

        f4acc accW0 = (f4acc){0.f, 0.f, 0.f, 0.f};
        f4acc accW1 = (f4acc){0.f, 0.f, 0.f, 0.f};
#pragma unroll
        for (int k = 0; k < 4; k++) {
            const int ko = 32 * k + 8 * quad;
            bfrag r0h = *(const bfrag*)&hhi[(rt0 * 16 + l16) * PSTR + ko];
            bfrag r0l = *(const bfrag*)&hlo[(rt0 * 16 + l16) * PSTR + ko];
            bfrag r1h = *(const bfrag*)&hhi[((rt0 + 1) * 16 + l16) * PSTR + ko];
            bfrag r1l = *(const bfrag*)&hlo[((rt0 + 1) * 16 + l16) * PSTR + ko];
            bfrag c0h = *(const bfrag*)&hhi[(ct0 * 16 + l16) * PSTR + ko];
            bfrag c0l = *(const bfrag*)&hlo[(ct0 * 16 + l16) * PSTR + ko];
            bfrag c1h = *(const bfrag*)&hhi[((ct0 + 1) * 16 + l16) * PSTR + ko];
            bfrag c1l = *(const bfrag*)&hlo[((ct0 + 1) * 16 + l16) * PSTR + ko];
            // A quadrant: 4 tiles x 3 products
            accA[0][0] = MFMA16(r0h, c0h, accA[0][0]);
            accA[0][0] = MFMA16(r0h, c0l, accA[0][0]);
            accA[0][0] = MFMA16(r0l, c0h, accA[0][0]);
            accA[0][1] = MFMA16(r0h, c1h, accA[0][1]);
            accA[0][1] = MFMA16(r0h, c1l, accA[0][1]);
            accA[0][1] = MFMA16(r0l, c1h, accA[0][1]);
            accA[1][0] = MFMA16(r1h, c0h, accA[1][0]);
            accA[1][0] = MFMA16(r1h, c0l, accA[1][0]);
            accA[1][0] = MFMA16(r1l, c0h, accA[1][0]);
            accA[1][1] = MFMA16(r1h, c1h, accA[1][1]);
            accA[1][1] = MFMA16(r1h, c1l, accA[1][1]);
            accA[1][1] = MFMA16(r1l, c1h, accA[1][1]);
            // Wh tiles (rows rt0, rt0+1; col jW), W frags in regs
            accW0 = MFMA16(r0h, wfh[k], accW0);
            accW0 = MFMA16(r0h, wfl[k], accW0);
            accW0 = MFMA16(r0l, wfh[k], accW0);
            accW1 = MFMA16(r1h, wfh[k], accW1);
            accW1 = MFMA16(r1h, wfl[k], accW1);
            accW1 = MFMA16(r1l, wfh[k], accW1);
        }
        // epilogue: scale rows by nrm, write Wh, reduce s1/s2 per row
        float* whout = Wh + (size_t)(b * T_ + t) * (C_ * O_);
#pragma unroll
        for (int i2 = 0; i2 < 2; i2++) {
            f4acc aw = i2 ? accW1 : accW0;
#pragma unroll
            for (int r = 0; r < 4; r++) {
                int row = (rt0 + i2) * 16 + quad * 4 + r;
                float val = aw[r] * nrm[row];
                whout[row * O_ + l16 + 16 * jW] = val;
                float v1 = val * ga1, v2 = val * ga2;
#pragma unroll
                for (int d = 1; d < 16; d <<= 1) {
                    v1 += __shfl_xor(v1, d);
                    v2 += __shfl_xor(v2, d);
                }
                if (l16 == 0) { s1p[jW][row] = v1; s2p[jW][row] = v2; }
            }
        }
        __syncthreads();  // (c) s1p/s2p ready; also: this-t frag reads done
        if (tid < 64) {
            s1[(b * T_ + t) * C_ + tid] = s1p[0][tid] + s1p[1][tid];
            s2[(b * T_ + t) * C_ + tid] = s2p[0][tid] + s2p[1][tid];
        }
    }
    // block-end: quadrants disjoint -> direct atomicAdd
#pragma unroll
    for (int i2 = 0; i2 < 2; i2++)
#pragma unroll
        for (int j2 = 0; j2 < 2; j2++)
#pragma unroll
            for (int r = 0; r < 4; r++) {
                int row = (rt0 + i2) * 16 + quad * 4 + r;
                int col = (ct0 + j2) * 16 + l16;
                atomicAdd(&A[b * (C_ * C_) + row * C_ + col], accA[i2][j2][r]);
            }
}

// ---------------------------------------------------------------------------
// K2: top-4 selection + symmetrize -> amask bitmask per (b,c). grid B, block 64
// ---------------------------------------------------------------------------
__global__ __launch_bounds__(64) void k_topk(const float* __restrict__ A,
                                             unsigned long long* __restrict__ amask) {
    int b = blockIdx.x;
    int c = threadIdx.x;
    __shared__ unsigned long long tk[C_];
    const float* row = A + b * (C_ * C_) + c * C_;
    unsigned long long sel = 0ULL;
    for (int r = 0; r < 4; r++) {
        float best = -1e30f;
        int bi = 0;
        for (int d = 0; d < C_; d++) {
            if (sel & (1ULL << d)) continue;
            float v = row[d];
            if (v > best) { best = v; bi = d; }
        }
        sel |= (1ULL << bi);
    }
    unsigned long long t = sel & ~(1ULL << c);
    tk[c] = t;
    __syncthreads();
    unsigned long long sym = t;
    for (int d = 0; d < C_; d++)
        if ((tk[d] >> c) & 1ULL) sym |= (1ULL << d);
    unsigned long long m = (1ULL << c);
    unsigned long long s2 = sym;
    while (s2) {
        int d = __ffsll(s2) - 1;
        s2 &= s2 - 1;
        if (row[d] > 0.f) m |= (1ULL << d);
    }
    amask[b * C_ + c] = m;
}

// ---------------------------------------------------------------------------
// K3: GAT attention + relu + pooling + FUSED lstm input projection.
// block 256 = 4 waves = 4 t's. grid B*T/4.
// Each wave stages its Wh[bt] tile (64x32 f32 = 8KB) into LDS with coalesced
// float4 loads; the divergent mask loop reads LDS instead of re-reading
// global rows. shm overlays the staged tile (phase A) and buf (phase B).
// FP order per output unchanged.
// ---------------------------------------------------------------------------
__global__ __launch_bounds__(256) void k_gat(
    const float* __restrict__ Wh, const float* __restrict__ s1,
    const float* __restrict__ s2, const unsigned long long* __restrict__ amask,
    const float* __restrict__ pool_w, const float* __restrict__ pool_b,
    const float* __restrict__ Wi_f, const float* __restrict__ b_f,
    const float* __restrict__ Wi_r, const float* __restrict__ b_r,
    float* __restrict__ gx) {
    int tg = blockIdx.x;
    int wv = threadIdx.x >> 6, c = threadIdx.x & 63;
    int bt = tg * 4 + wv;
    int b = bt >> 8;
    __shared__ float shm[4][C_][36];   // phase A: staged Wh[bt]; phase B: buf
    __shared__ float s2s[4][C_];
    __shared__ float hp[4][H_];

    // stage Wh[bt] -> shm[wv] (wave-local, coalesced; no block sync needed)
    {
        const float4* src = (const float4*)(Wh + (size_t)bt * (C_ * O_));
#pragma unroll
        for (int q = 0; q < 8; q++) {
            int f = c + 64 * q;            // float4 index in the 512-f4 tile
            float4 v = src[f];
            *(float4*)&shm[wv][f >> 3][4 * (f & 7)] = v;
        }
    }

    s2s[wv][c] = s2[bt * C_ + c];
    float s1c = s1[bt * C_ + c];
    unsigned long long m = amask[b * C_ + c];
    __syncthreads();

    float mx = -1e30f;
    unsigned long long mm = m;
    while (mm) {
        int d = __ffsll(mm) - 1; mm &= mm - 1;
        float v = s1c + s2s[wv][d];
        v = v > 0.f ? v : 0.2f * v;
        mx = fmaxf(mx, v);
    }
    float ssum = 0.f;
    mm = m;
    while (mm) {
        int d = __ffsll(mm) - 1; mm &= mm - 1;
        float v = s1c + s2s[wv][d];
        v = v > 0.f ? v : 0.2f * v;
        ssum += __expf(v - mx);
    }
    float inv = 1.0f / ssum;
    float g[O_];
#pragma unroll
    for (int i = 0; i < O_; i++) g[i] = 0.f;
    mm = m;
    while (mm) {
        int d = __ffsll(mm) - 1; mm &= mm - 1;
        float v = s1c + s2s[wv][d];
        v = v > 0.f ? v : 0.2f * v;
        float a = __expf(v - mx);
        const float* wr = &shm[wv][d][0];
#pragma unroll
        for (int q = 0; q < 8; q++) {
            float4 w4 = *(const float4*)&wr[4 * q];
            g[4 * q + 0] += a * w4.x;
            g[4 * q + 1] += a * w4.y;
            g[4 * q + 2] += a * w4.z;
            g[4 * q + 3] += a * w4.w;
        }
    }
    float lg = pool_b[0];
#pragma unroll
    for (int i = 0; i < O_; i++) {
        g[i] = fmaxf(g[i] * inv, 0.f);
        lg += g[i] * pool_w[i];
    }
    float wmx = lg;
#pragma unroll
    for (int s = 1; s < 64; s <<= 1) wmx = fmaxf(wmx, __shfl_xor(wmx, s));
    float we = __expf(lg - wmx);
    float wsum = we;
#pragma unroll
    for (int s = 1; s < 64; s <<= 1) wsum += __shfl_xor(wsum, s);
    float wcf = we / wsum;
    // phase B: reuse shm[wv] as buf (staged tile fully consumed by this wave)
#pragma unroll
    for (int i = 0; i < O_; i++) shm[wv][c][i] = g[i] * wcf;
    __syncthreads();
    {
        int wt = threadIdx.x >> 6, o = threadIdx.x & 31, hf = (threadIdx.x >> 5) & 1;
        float sacc = 0.f;
#pragma unroll 8
        for (int d = hf * 32; d < hf * 32 + 32; d++) sacc += shm[wt][d][o];
        sacc += __shfl_xor(sacc, 32);
        if (hf == 0) hp[wt][o] = sacc;
    }
    __syncthreads();
    // fused lstm_pre: thread = (dir = tid>>7, col = tid&127), row-major gx
    {
        int dir = threadIdx.x >> 7, col = threadIdx.x & 127;
        const float* Wi = dir ? Wi_r : Wi_f;
        const float* bb = dir ? b_r : b_f;
        float bv = bb[col];
        float a0 = bv, a1 = bv, a2 = bv, a3 = bv;
#pragma unroll
        for (int k = 0; k < H_; k++) {
            float wvv = Wi[k * G4_ + col];
            a0 = fmaf(hp[0][k], wvv, a0);
            a1 = fmaf(hp[1][k], wvv, a1);
            a2 = fmaf(hp[2][k], wvv, a2);
            a3 = fmaf(hp[3][k], wvv, a3);
        }
        size_t base = (size_t)dir * 4096 + (size_t)tg * 4;
        gx[(base + 0) * G4_ + col] = a0;
        gx[(base + 1) * G4_ + col] = a1;
        gx[(base + 2) * G4_ + col] = a2;
        gx[(base + 3) * G4_ + col] = a3;
    }
}

// ---------------------------------------------------------------------------
// K4+K5 FUSED: LSTM recurrence + temporal attention/LN/fc head.
// grid B_, block 256 (4 waves), hcat kept in DYNAMIC LDS (64KB) -- never
// touches global. Waves 0/1 run the fwd/rev chains (round-2 verbatim LSTM
// body: 93us local optimum, 6 restructures all regressed). Waves 2/3
// pre-stage taW into LDS during the recurrence, then wait at the barrier.
// After the barrier all 256 threads run the old k_final body with hcat
// reads redirected to LDS. Saves: one launch+drain, hcat global round-trip,
// k_final's cold Wl staging. FP order identical everywhere.
// __launch_bounds__(256,1): LDS (~84KB) caps at 1 block/CU anyway; keep the
// RA at full VGPR budget (round-1 lesson: never let the occupancy heuristic
// cap regs on a reg-hungry kernel).
// ---------------------------------------------------------------------------
#define WW(k) float2 ww##k = make_float2(Wd[(k) * G4_ + lane], Wd[(k) * G4_ + lane + 64]);
#define KST(k, Aq) { float hk = readlane_f(h, k); \
    Aq.x = fmaf(hk, ww##k.x, Aq.x); Aq.y = fmaf(hk, ww##k.y, Aq.y); }

__global__ __launch_bounds__(256, 1) void k_lstm_final(
    const float* __restrict__ gx,
    const float* __restrict__ Whf, const float* __restrict__ Whr,
    const float* __restrict__ taW, const float* __restrict__ tab,
    const float* __restrict__ tav,
    const float* __restrict__ lng, const float* __restrict__ lnb,
    const float* __restrict__ w1, const float* __restrict__ b1,
    const float* __restrict__ w2, const float* __restrict__ b2,
    float* __restrict__ out) {
    extern __shared__ float hcd[];          // [T_][64] = 64 KB dynamic
    float (*hc)[64] = (float(*)[64])hcd;
    __shared__ float Wl[64 * 64];
    __shared__ float al[T_];
    __shared__ float wred[4];
    __shared__ float ctxp[4][64];
    __shared__ float ctx[64];
    __shared__ float a1s[32];

    const int b = blockIdx.x;
    const int tid = threadIdx.x;
    const int wavid = tid >> 6, lane = tid & 63;

    if (wavid >= 2) {
        // stage taW while waves 0/1 run the recurrence
        for (int i = tid - 128; i < 4096; i += 128) Wl[i] = taW[i];
    } else {
        const int dir = wavid;              // wave0 = fwd, wave1 = rev
        const float* Wd = dir ? Whr : Whf;
        WW(0) WW(1) WW(2) WW(3) WW(4) WW(5) WW(6) WW(7)
        WW(8) WW(9) WW(10) WW(11) WW(12) WW(13) WW(14) WW(15)
        WW(16) WW(17) WW(18) WW(19) WW(20) WW(21) WW(22) WW(23)
        WW(24) WW(25) WW(26) WW(27) WW(28) WW(29) WW(30) WW(31)

        const float* gxb = gx + ((size_t)dir * 4096 + b * T_) * G4_;
        float h = 0.f, cst = 0.f;
        const int dt = dir ? -1 : 1;
        int t = dir ? (T_ - 1) : 0;
        float g0n = gxb[t * G4_ + lane], g1n = gxb[t * G4_ + lane + 64];
        const float half_sel = (lane < 32) ? 2.f : 1.f;
        for (int s = 0; s < T_; s++) {
            int tn = t + dt;
            float2 A0 = make_float2(g0n, g1n);
            float2 A1 = make_float2(0.f, 0.f);
            float2 A2 = make_float2(0.f, 0.f);
            float2 A3 = make_float2(0.f, 0.f);
            if (s < T_ - 1) {
                g0n = gxb[tn * G4_ + lane];
                g1n = gxb[tn * G4_ + lane + 64];
            }
            KST(0, A0)  KST(1, A1)  KST(2, A2)  KST(3, A3)
            KST(4, A0)  KST(5, A1)  KST(6, A2)  KST(7, A3)
            KST(8, A0)  KST(9, A1)  KST(10, A2) KST(11, A3)
            KST(12, A0) KST(13, A1) KST(14, A2) KST(15, A3)
            KST(16, A0) KST(17, A1) KST(18, A2) KST(19, A3)
            KST(20, A0) KST(21, A1) KST(22, A2) KST(23, A3)
            KST(24, A0) KST(25, A1) KST(26, A2) KST(27, A3)
            KST(28, A0) KST(29, A1) KST(30, A2) KST(31, A3)
            float g0 = (A0.x + A1.x) + (A2.x + A3.x);
            float g1 = (A0.y + A1.y) + (A2.y + A3.y);
            float sA = sigm_f(g0);
            float u = sigm_f(half_sel * g1);
            float sB = (lane < 32) ? fmaf(2.f, u, -1.f) : u;
            float sf = __shfl(sA, (lane & 31) + 32);
            float so = __shfl(sB, (lane & 31) + 32);
            cst = fmaf(sf, cst, sA * sB);
            float hn = so * tanh_f(cst);
            h = hn;
            if (lane < H_) hc[t][dir * H_ + lane] = hn;
            t = tn;
        }
    }
    __syncthreads();   // hcat + Wl ready

    // ---- former k_final body; thread = its t; hcat reads -> LDS ----
    const int t = tid;
    float4 hr[16];
#pragma unroll
    for (int i = 0; i < 16; i++) hr[i] = *(const float4*)&hc[t][4 * i];
    float sc = 0.f;
    for (int j = 0; j < 64; j++) {
        float s = tab[j];
#pragma unroll
        for (int k4 = 0; k4 < 16; k4++) {
            float4 h4 = hr[k4];
            const float* wcol = &Wl[(4 * k4) * 64 + j];
            s += h4.x * wcol[0] + h4.y * wcol[64] + h4.z * wcol[128] + h4.w * wcol[192];
        }
        sc += tanhf(s) * tav[j];
    }
    sc *= (1.0f / 1.5f);
    float m = sc;
#pragma unroll
    for (int s_ = 1; s_ < 64; s_ <<= 1) m = fmaxf(m, __shfl_xor(m, s_));
    if (lane == 0) wred[wavid] = m;
    __syncthreads();
    m = fmaxf(fmaxf(wred[0], wred[1]), fmaxf(wred[2], wred[3]));
    float e = __expf(sc - m);
    float ssum = e;
#pragma unroll
    for (int s_ = 1; s_ < 64; s_ <<= 1) ssum += __shfl_xor(ssum, s_);
    __syncthreads();
    if (lane == 0) wred[wavid] = ssum;
    __syncthreads();
    float S = wred[0] + wred[1] + wred[2] + wred[3];
    al[t] = e / S;
    __syncthreads();
    // ctx partials: thread = (part = t>>6, o = t&63)
    {
        int o = t & 63, part = t >> 6;
        float cacc = 0.f;
        for (int tt = part * 64; tt < part * 64 + 64; tt++)
            cacc += al[tt] * hc[tt][o];
        ctxp[part][o] = cacc;
    }
    __syncthreads();
    if (t < 64) {
        float ctxo = ctxp[0][t] + ctxp[1][t] + ctxp[2][t] + ctxp[3][t];
        float sv = ctxo, sq = ctxo * ctxo;
#pragma unroll
        for (int s_ = 1; s_ < 64; s_ <<= 1) {
            sv += __shfl_xor(sv, s_);
            sq += __shfl_xor(sq, s_);
        }
        float mu = sv * (1.f / 64.f);
        float var = sq * (1.f / 64.f) - mu * mu;
        ctx[t] = (ctxo - mu) / sqrtf(var + 1e-5f) * lng[t] + lnb[t];
    }
    __syncthreads();
    if (t < 32) {
        float s = b1[t];
        for (int k = 0; k < 64; k++) s += ctx[k] * w1[k * 32 + t];
        a1s[t] = fmaxf(s, 0.f);
    }
    __syncthreads();
    if (t < 3) {
        float s = b2[t];
        for (int k = 0; k < 32; k++) s += a1s[k] * w2[k * 3 + t];
        out[b * 3 + t] = s;
    }
}

// ---------------------------------------------------------------------------
extern "C" void kernel_launch(void* const* d_in, const int* in_sizes, int n_in,
                              void* d_out, int out_size, void* d_ws, size_t ws_size,
                              hipStream_t stream) {
    const float* x          = (const float*)d_in[0];
    const float* spectral_w = (const float*)d_in[1];
    const float* gat_W      = (const float*)d_in[2];
    const float* gat_a      = (const float*)d_in[3];
    const float* pool_w     = (const float*)d_in[4];
    const float* pool_b     = (const float*)d_in[5];
    const float* lstm_Wi_f  = (const float*)d_in[6];
    const float* lstm_Wh_f  = (const float*)d_in[7];
    const float* lstm_b_f   = (const float*)d_in[8];
    const float* lstm_Wi_r  = (const float*)d_in[9];
    const float* lstm_Wh_r  = (const float*)d_in[10];
    const float* lstm_b_r   = (const float*)d_in[11];
    const float* ta_W       = (const float*)d_in[12];
    const float* ta_b       = (const float*)d_in[13];
    const float* ta_v       = (const float*)d_in[14];
    const float* ln_g       = (const float*)d_in[15];
    const float* ln_b       = (const float*)d_in[16];
    const float* fc1_w      = (const float*)d_in[17];
    const float* fc1_b      = (const float*)d_in[18];
    const float* fc2_w      = (const float*)d_in[19];
    const float* fc2_b      = (const float*)d_in[20];
    float* out = (float*)d_out;

    float* ws = (float*)d_ws;
    float* sw    = ws + 0;                         // 8192
    float* A     = ws + 8192;                      // 65536
    unsigned long long* amask = (unsigned long long*)(ws + 73728);  // 1024 u64
    float* Wh    = ws + 75776;                     // 8388608
    float* s1    = ws + 8464384;                   // 262144
    float* s2    = ws + 8726528;                   // 262144
    float* gx    = ws + 9119744;                   // 1048576 (row-major)

    hipMemsetAsync(A, 0, (size_t)C_ * C_ * B_ * sizeof(float), stream);
    k_sw<<<C_, 64, 0, stream>>>(spectral_w, sw);
    k_phase1<<<dim3(B_, T_ / TCP), 256, 0, stream>>>(x, sw, gat_W, gat_a, A, Wh, s1, s2);
    k_topk<<<B_, 64, 0, stream>>>(A, amask);
    k_gat<<<B_ * T_ / 4, 256, 0, stream>>>(Wh, s1, s2, amask, pool_w, pool_b,
                                           lstm_Wi_f, lstm_b_f, lstm_Wi_r, lstm_b_r, gx);
    k_lstm_final<<<B_, 256, (size_t)T_ * 64 * sizeof(float), stream>>>(
        gx, lstm_Wh_f, lstm_Wh_r, ta_W, ta_b, ta_v, ln_g, ln_b,
        fc1_w, fc1_b, fc2_w, fc2_b, out);
}

// Round 11
// 401.788 us; speedup vs baseline: 1.3127x; 1.0105x over previous
//
#include <hip/hip_runtime.h>
#include <hip/hip_bf16.h>

// Dims
#define B_  16
#define T_  256
#define C_  64
#define F_  128
#define O_  32   // GO
#define H_  32
#define G4_ 128  // 4*H

typedef __attribute__((ext_vector_type(8))) short bfrag;
typedef __attribute__((ext_vector_type(4))) float f4acc;

__device__ __forceinline__ unsigned short f2bf(float v) {
    union { float f; unsigned u; } c; c.f = v;
    unsigned r = c.u + 0x7FFF + ((c.u >> 16) & 1);
    return (unsigned short)(r >> 16);
}
__device__ __forceinline__ float bf2f(unsigned short b) {
    union { float f; unsigned u; } c; c.u = ((unsigned)b) << 16; return c.f;
}
__device__ __forceinline__ float sigm_f(float x) {
    return __builtin_amdgcn_rcpf(1.f + __expf(-x));
}
__device__ __forceinline__ float tanh_f(float x) {
    float e = __expf(2.f * x);
    return 1.f - 2.f * __builtin_amdgcn_rcpf(e + 1.f);
}
__device__ __forceinline__ float readlane_f(float v, int l) {
    return __int_as_float(__builtin_amdgcn_readlane(__float_as_int(v), l));
}

// ---------------------------------------------------------------------------
// K0: softmax of spectral_w rows (64 rows of 128)
// ---------------------------------------------------------------------------
__global__ __launch_bounds__(64) void k_sw(const float* __restrict__ w,
                                           float* __restrict__ sw) {
    int c = blockIdx.x, lane = threadIdx.x;
    const float* row = w + c * F_;
    float v0 = row[lane], v1 = row[lane + 64];
    float m = fmaxf(v0, v1);
#pragma unroll
    for (int s = 1; s < 64; s <<= 1) m = fmaxf(m, __shfl_xor(m, s));
    float e0 = __expf(v0 - m), e1 = __expf(v1 - m);
    float s = e0 + e1;
#pragma unroll
    for (int s_ = 1; s_ < 64; s_ <<= 1) s += __shfl_xor(s, s_);
    sw[c * F_ + lane] = e0 / s;
    sw[c * F_ + lane + 64] = e1 / s;
}

// ---------------------------------------------------------------------------
// K1: MFMA phase1. split-bf16 (hi/lo) Hn planes in LDS.
// grid (B, T/TCP), block 256. TCP=1 (was 2): 4096 blocks = 16 blocks/CU of
// work with 4 resident -> deeper oversubscription desynchronizes barrier
// phases so load bursts overlap other blocks' MFMA phases (same mechanism
// as the round-2 TCP 4->2 win). Prologue doubles (~1-2us chip-wide);
// A-atomics double to 16.7M on an L2-hot 64KB array (spread across
// desynced block-ends).
// ---------------------------------------------------------------------------
#define TCP 1
#define PSTR 136   // bf16 elements per row (272 B): 16B-aligned, bank-uniform

#define MFMA16(a, b, c) __builtin_amdgcn_mfma_f32_16x16x32_bf16(a, b, c, 0, 0, 0)

__global__ __launch_bounds__(256) void k_phase1(
    const float* __restrict__ x, const float* __restrict__ sw,
    const float* __restrict__ gat_W, const float* __restrict__ gat_a,
    float* __restrict__ A, float* __restrict__ Wh,
    float* __restrict__ s1, float* __restrict__ s2) {
    const int b = blockIdx.x, tc = blockIdx.y, tid = threadIdx.x;
    const int wv = tid >> 6, lane = tid & 63;
    const int quad = lane >> 4, l16 = lane & 15;

    __shared__ unsigned short hhi[64 * PSTR];
    __shared__ unsigned short hlo[64 * PSTR];
    __shared__ float nrm[64];
    __shared__ float s1p[2][64], s2p[2][64];

    // sw regs (same (c,f) slice every t)
    float4 swr[8];
    {
        const float4* sw4 = (const float4*)sw;
#pragma unroll
        for (int i = 0; i < 8; i++) swr[i] = sw4[tid + 256 * i];
    }

    const int rt0 = (wv >> 1) * 2;  // row-tile base {0,2}
    const int ct0 = (wv & 1) * 2;   // col-tile base {0,2}
    const int jW = wv & 1;          // Wh col-tile

    // W fragments (hi/lo) for this wave's jW, ksteps 0..3, held in regs
    bfrag wfh[4], wfl[4];
    {
        const int n = l16 + 16 * jW;
#pragma unroll
        for (int k = 0; k < 4; k++) {
            union { unsigned short u[8]; bfrag v; } Hu, Lu;
#pragma unroll
            for (int u = 0; u < 8; u++) {
                float v = gat_W[(32 * k + quad * 8 + u) * O_ + n];
                unsigned short hb = f2bf(v);
                Hu.u[u] = hb;
                Lu.u[u] = f2bf(v - bf2f(hb));
            }
            wfh[k] = Hu.v;
            wfl[k] = Lu.v;
        }
    }
    const float ga1 = gat_a[l16 + 16 * jW];
    const float ga2 = gat_a[O_ + l16 + 16 * jW];

    f4acc accA[2][2];
#pragma unroll
    for (int i = 0; i < 2; i++)
#pragma unroll
        for (int j = 0; j < 2; j++) accA[i][j] = (f4acc){0.f, 0.f, 0.f, 0.f};

    for (int tt = 0; tt < TCP; ++tt) {
        const int t = tc * TCP + tt;
        const float4* xg = (const float4*)(x + ((size_t)(b * T_ + t) << 13));
        float4 xr[8];
#pragma unroll
        for (int i = 0; i < 8; i++) xr[i] = xg[tid + 256 * i];

        float invn_[8];
#pragma unroll
        for (int i = 0; i < 8; i++) {
            float4 v = xr[i], s = swr[i];
            v.x *= s.x; v.y *= s.y; v.z *= s.z; v.w *= s.w;
            xr[i] = v;
            float ss = v.x * v.x + v.y * v.y + v.z * v.z + v.w * v.w;
#pragma unroll
            for (int d = 1; d < 32; d <<= 1) ss += __shfl_xor(ss, d);
            float nv = sqrtf(ss) + 1e-8f;
            invn_[i] = 1.0f / nv;
            if ((tid & 31) == 0) nrm[(tid >> 5) + 8 * i] = nv;
        }
        // split + write planes: row c=(tid>>5)+8i, f = 4*(tid&31)
#pragma unroll
        for (int i = 0; i < 8; i++) {
            int c = (tid >> 5) + 8 * i;
            float4 v = xr[i];
            float iv = invn_[i];
            float a0 = v.x * iv, a1 = v.y * iv, a2 = v.z * iv, a3 = v.w * iv;
            union { unsigned short u[4]; unsigned long long q; } Hq, Lq;
            unsigned short h0 = f2bf(a0), h1 = f2bf(a1), h2 = f2bf(a2), h3 = f2bf(a3);
            Hq.u[0] = h0; Hq.u[1] = h1; Hq.u[2] = h2; Hq.u[3] = h3;
            Lq.u[0] = f2bf(a0 - bf2f(h0));
            Lq.u[1] = f2bf(a1 - bf2f(h1));
            Lq.u[2] = f2bf(a2 - bf2f(h2));
            Lq.u[3] = f2bf(a3 - bf2f(h3));
            int off = c * PSTR + 4 * (tid & 31);
            *(unsigned long long*)&hhi[off] = Hq.q;
            *(unsigned long long*)&hlo[off] = Lq.q;
        }
        __syncthreads();  // (b) planes ready

        f4acc accW0 = (f4acc){0.f, 0.f, 0.f, 0.f};
        f4acc accW1 = (f4acc){0.f, 0.f, 0.f, 0.f};
#pragma unroll
        for (int k = 0; k < 4; k++) {
            const int ko = 32 * k + 8 * quad;
            bfrag r0h = *(const bfrag*)&hhi[(rt0 * 16 + l16) * PSTR + ko];
            bfrag r0l = *(const bfrag*)&hlo[(rt0 * 16 + l16) * PSTR + ko];
            bfrag r1h = *(const bfrag*)&hhi[((rt0 + 1) * 16 + l16) * PSTR + ko];
            bfrag r1l = *(const bfrag*)&hlo[((rt0 + 1) * 16 + l16) * PSTR + ko];
            bfrag c0h = *(const bfrag*)&hhi[(ct0 * 16 + l16) * PSTR + ko];
            bfrag c0l = *(const bfrag*)&hlo[(ct0 * 16 + l16) * PSTR + ko];
            bfrag c1h = *(const bfrag*)&hhi[((ct0 + 1) * 16 + l16) * PSTR + ko];
            bfrag c1l = *(const bfrag*)&hlo[((ct0 + 1) * 16 + l16) * PSTR + ko];
            // A quadrant: 4 tiles x 3 products
            accA[0][0] = MFMA16(r0h, c0h, accA[0][0]);
            accA[0][0] = MFMA16(r0h, c0l, accA[0][0]);
            accA[0][0] = MFMA16(r0l, c0h, accA[0][0]);
            accA[0][1] = MFMA16(r0h, c1h, accA[0][1]);
            accA[0][1] = MFMA16(r0h, c1l, accA[0][1]);
            accA[0][1] = MFMA16(r0l, c1h, accA[0][1]);
            accA[1][0] = MFMA16(r1h, c0h, accA[1][0]);
            accA[1][0] = MFMA16(r1h, c0l, accA[1][0]);
            accA[1][0] = MFMA16(r1l, c0h, accA[1][0]);
            accA[1][1] = MFMA16(r1h, c1h, accA[1][1]);
            accA[1][1] = MFMA16(r1h, c1l, accA[1][1]);
            accA[1][1] = MFMA16(r1l, c1h, accA[1][1]);
            // Wh tiles (rows rt0, rt0+1; col jW), W frags in regs
            accW0 = MFMA16(r0h, wfh[k], accW0);
            accW0 = MFMA16(r0h, wfl[k], accW0);
            accW0 = MFMA16(r0l, wfh[k], accW0);
            accW1 = MFMA16(r1h, wfh[k], accW1);
            accW1 = MFMA16(r1h, wfl[k], accW1);
            accW1 = MFMA16(r1l, wfh[k], accW1);
        }
        // epilogue: scale rows by nrm, write Wh, reduce s1/s2 per row
        float* whout = Wh + (size_t)(b * T_ + t) * (C_ * O_);
#pragma unroll
        for (int i2 = 0; i2 < 2; i2++) {
            f4acc aw = i2 ? accW1 : accW0;
#pragma unroll
            for (int r = 0; r < 4; r++) {
                int row = (rt0 + i2) * 16 + quad * 4 + r;
                float val = aw[r] * nrm[row];
                whout[row * O_ + l16 + 16 * jW] = val;
                float v1 = val * ga1, v2 = val * ga2;
#pragma unroll
                for (int d = 1; d < 16; d <<= 1) {
                    v1 += __shfl_xor(v1, d);
                    v2 += __shfl_xor(v2, d);
                }
                if (l16 == 0) { s1p[jW][row] = v1; s2p[jW][row] = v2; }
            }
        }
        __syncthreads();  // (c) s1p/s2p ready; also: this-t frag reads done
        if (tid < 64) {
            s1[(b * T_ + t) * C_ + tid] = s1p[0][tid] + s1p[1][tid];
            s2[(b * T_ + t) * C_ + tid] = s2p[0][tid] + s2p[1][tid];
        }
    }
    // block-end: quadrants disjoint -> direct atomicAdd
#pragma unroll
    for (int i2 = 0; i2 < 2; i2++)
#pragma unroll
        for (int j2 = 0; j2 < 2; j2++)
#pragma unroll
            for (int r = 0; r < 4; r++) {
                int row = (rt0 + i2) * 16 + quad * 4 + r;
                int col = (ct0 + j2) * 16 + l16;
                atomicAdd(&A[b * (C_ * C_) + row * C_ + col], accA[i2][j2][r]);
            }
}

// ---------------------------------------------------------------------------
// K2: top-4 selection + symmetrize -> amask bitmask per (b,c). grid B, block 64
// ---------------------------------------------------------------------------
__global__ __launch_bounds__(64) void k_topk(const float* __restrict__ A,
                                             unsigned long long* __restrict__ amask) {
    int b = blockIdx.x;
    int c = threadIdx.x;
    __shared__ unsigned long long tk[C_];
    const float* row = A + b * (C_ * C_) + c * C_;
    unsigned long long sel = 0ULL;
    for (int r = 0; r < 4; r++) {
        float best = -1e30f;
        int bi = 0;
        for (int d = 0; d < C_; d++) {
            if (sel & (1ULL << d)) continue;
            float v = row[d];
            if (v > best) { best = v; bi = d; }
        }
        sel |= (1ULL << bi);
    }
    unsigned long long t = sel & ~(1ULL << c);
    tk[c] = t;
    __syncthreads();
    unsigned long long sym = t;
    for (int d = 0; d < C_; d++)
        if ((tk[d] >> c) & 1ULL) sym |= (1ULL << d);
    unsigned long long m = (1ULL << c);
    unsigned long long s2 = sym;
    while (s2) {
        int d = __ffsll(s2) - 1;
        s2 &= s2 - 1;
        if (row[d] > 0.f) m |= (1ULL << d);
    }
    amask[b * C_ + c] = m;
}

// ---------------------------------------------------------------------------
// K3: GAT attention + relu + pooling + FUSED lstm input projection.
// block 256 = 4 waves = 4 t's. grid B*T/4.
// Each wave stages its Wh[bt] tile (64x32 f32 = 8KB) into LDS with coalesced
// float4 loads; the divergent mask loop reads LDS instead of re-reading
// global rows. shm overlays the staged tile (phase A) and buf (phase B).
// FP order per output unchanged.
// ---------------------------------------------------------------------------
__global__ __launch_bounds__(256) void k_gat(
    const float* __restrict__ Wh, const float* __restrict__ s1,
    const float* __restrict__ s2, const unsigned long long* __restrict__ amask,
    const float* __restrict__ pool_w, const float* __restrict__ pool_b,
    const float* __restrict__ Wi_f, const float* __restrict__ b_f,
    const float* __restrict__ Wi_r, const float* __restrict__ b_r,
    float* __restrict__ gx) {
    int tg = blockIdx.x;
    int wv = threadIdx.x >> 6, c = threadIdx.x & 63;
    int bt = tg * 4 + wv;
    int b = bt >> 8;
    __shared__ float shm[4][C_][36];   // phase A: staged Wh[bt]; phase B: buf
    __shared__ float s2s[4][C_];
    __shared__ float hp[4][H_];

    // stage Wh[bt] -> shm[wv] (wave-local, coalesced; no block sync needed)
    {
        const float4* src = (const float4*)(Wh + (size_t)bt * (C_ * O_));
#pragma unroll
        for (int q = 0; q < 8; q++) {
            int f = c + 64 * q;            // float4 index in the 512-f4 tile
            float4 v = src[f];
            *(float4*)&shm[wv][f >> 3][4 * (f & 7)] = v;
        }
    }

    s2s[wv][c] = s2[bt * C_ + c];
    float s1c = s1[bt * C_ + c];
    unsigned long long m = amask[b * C_ + c];
    __syncthreads();

    float mx = -1e30f;
    unsigned long long mm = m;
    while (mm) {
        int d = __ffsll(mm) - 1; mm &= mm - 1;
        float v = s1c + s2s[wv][d];
        v = v > 0.f ? v : 0.2f * v;
        mx = fmaxf(mx, v);
    }
    float ssum = 0.f;
    mm = m;
    while (mm) {
        int d = __ffsll(mm) - 1; mm &= mm - 1;
        float v = s1c + s2s[wv][d];
        v = v > 0.f ? v : 0.2f * v;
        ssum += __expf(v - mx);
    }
    float inv = 1.0f / ssum;
    float g[O_];
#pragma unroll
    for (int i = 0; i < O_; i++) g[i] = 0.f;
    mm = m;
    while (mm) {
        int d = __ffsll(mm) - 1; mm &= mm - 1;
        float v = s1c + s2s[wv][d];
        v = v > 0.f ? v : 0.2f * v;
        float a = __expf(v - mx);
        const float* wr = &shm[wv][d][0];
#pragma unroll
        for (int q = 0; q < 8; q++) {
            float4 w4 = *(const float4*)&wr[4 * q];
            g[4 * q + 0] += a * w4.x;
            g[4 * q + 1] += a * w4.y;
            g[4 * q + 2] += a * w4.z;
            g[4 * q + 3] += a * w4.w;
        }
    }
    float lg = pool_b[0];
#pragma unroll
    for (int i = 0; i < O_; i++) {
        g[i] = fmaxf(g[i] * inv, 0.f);
        lg += g[i] * pool_w[i];
    }
    float wmx = lg;
#pragma unroll
    for (int s = 1; s < 64; s <<= 1) wmx = fmaxf(wmx, __shfl_xor(wmx, s));
    float we = __expf(lg - wmx);
    float wsum = we;
#pragma unroll
    for (int s = 1; s < 64; s <<= 1) wsum += __shfl_xor(wsum, s);
    float wcf = we / wsum;
    // phase B: reuse shm[wv] as buf (staged tile fully consumed by this wave)
#pragma unroll
    for (int i = 0; i < O_; i++) shm[wv][c][i] = g[i] * wcf;
    __syncthreads();
    {
        int wt = threadIdx.x >> 6, o = threadIdx.x & 31, hf = (threadIdx.x >> 5) & 1;
        float sacc = 0.f;
#pragma unroll 8
        for (int d = hf * 32; d < hf * 32 + 32; d++) sacc += shm[wt][d][o];
        sacc += __shfl_xor(sacc, 32);
        if (hf == 0) hp[wt][o] = sacc;
    }
    __syncthreads();
    // fused lstm_pre: thread = (dir = tid>>7, col = tid&127), row-major gx
    {
        int dir = threadIdx.x >> 7, col = threadIdx.x & 127;
        const float* Wi = dir ? Wi_r : Wi_f;
        const float* bb = dir ? b_r : b_f;
        float bv = bb[col];
        float a0 = bv, a1 = bv, a2 = bv, a3 = bv;
#pragma unroll
        for (int k = 0; k < H_; k++) {
            float wvv = Wi[k * G4_ + col];
            a0 = fmaf(hp[0][k], wvv, a0);
            a1 = fmaf(hp[1][k], wvv, a1);
            a2 = fmaf(hp[2][k], wvv, a2);
            a3 = fmaf(hp[3][k], wvv, a3);
        }
        size_t base = (size_t)dir * 4096 + (size_t)tg * 4;
        gx[(base + 0) * G4_ + col] = a0;
        gx[(base + 1) * G4_ + col] = a1;
        gx[(base + 2) * G4_ + col] = a2;
        gx[(base + 3) * G4_ + col] = a3;
    }
}

// ---------------------------------------------------------------------------
// K4+K5 FUSED: LSTM recurrence + temporal attention/LN/fc head.
// grid B_, block 256 (4 waves), hcat in DYNAMIC LDS (64KB). Waves 0/1 run
// the fwd/rev chains (round-2 verbatim body); waves 2/3 pre-stage taW.
// ROUND-10 FIX: __launch_bounds__(256,1) left the RA's occupancy heuristic
// in charge -> VGPR_Count=52, the 64 weight float2s went to AGPR/reload
// (per-use v_accvgpr_read overhead). The 2nd launch_bounds arg is only a
// MIN (same trap as the original R3/R4 lesson). Hard-pin with
// amdgpu_waves_per_eu(1,1) like the standalone 93us kernel had.
// ---------------------------------------------------------------------------
#define WW(k) float2 ww##k = make_float2(Wd[(k) * G4_ + lane], Wd[(k) * G4_ + lane + 64]);
#define KST(k, Aq) { float hk = readlane_f(h, k); \
    Aq.x = fmaf(hk, ww##k.x, Aq.x); Aq.y = fmaf(hk, ww##k.y, Aq.y); }

__global__ void __attribute__((amdgpu_flat_work_group_size(256, 256)))
__attribute__((amdgpu_waves_per_eu(1, 1))) k_lstm_final(
    const float* __restrict__ gx,
    const float* __restrict__ Whf, const float* __restrict__ Whr,
    const float* __restrict__ taW, const float* __restrict__ tab,
    const float* __restrict__ tav,
    const float* __restrict__ lng, const float* __restrict__ lnb,
    const float* __restrict__ w1, const float* __restrict__ b1,
    const float* __restrict__ w2, const float* __restrict__ b2,
    float* __restrict__ out) {
    extern __shared__ float hcd[];          // [T_][64] = 64 KB dynamic
    float (*hc)[64] = (float(*)[64])hcd;
    __shared__ float Wl[64 * 64];
    __shared__ float al[T_];
    __shared__ float wred[4];
    __shared__ float ctxp[4][64];
    __shared__ float ctx[64];
    __shared__ float a1s[32];

    const int b = blockIdx.x;
    const int tid = threadIdx.x;
    const int wavid = tid >> 6, lane = tid & 63;

    if (wavid >= 2) {
        // stage taW while waves 0/1 run the recurrence
        for (int i = tid - 128; i < 4096; i += 128) Wl[i] = taW[i];
    } else {
        const int dir = wavid;              // wave0 = fwd, wave1 = rev
        const float* Wd = dir ? Whr : Whf;
        WW(0) WW(1) WW(2) WW(3) WW(4) WW(5) WW(6) WW(7)
        WW(8) WW(9) WW(10) WW(11) WW(12) WW(13) WW(14) WW(15)
        WW(16) WW(17) WW(18) WW(19) WW(20) WW(21) WW(22) WW(23)
        WW(24) WW(25) WW(26) WW(27) WW(28) WW(29) WW(30) WW(31)

        const float* gxb = gx + ((size_t)dir * 4096 + b * T_) * G4_;
        float h = 0.f, cst = 0.f;
        const int dt = dir ? -1 : 1;
        int t = dir ? (T_ - 1) : 0;
        float g0n = gxb[t * G4_ + lane], g1n = gxb[t * G4_ + lane + 64];
        const float half_sel = (lane < 32) ? 2.f : 1.f;
        for (int s = 0; s < T_; s++) {
            int tn = t + dt;
            float2 A0 = make_float2(g0n, g1n);
            float2 A1 = make_float2(0.f, 0.f);
            float2 A2 = make_float2(0.f, 0.f);
            float2 A3 = make_float2(0.f, 0.f);
            if (s < T_ - 1) {
                g0n = gxb[tn * G4_ + lane];
                g1n = gxb[tn * G4_ + lane + 64];
            }
            KST(0, A0)  KST(1, A1)  KST(2, A2)  KST(3, A3)
            KST(4, A0)  KST(5, A1)  KST(6, A2)  KST(7, A3)
            KST(8, A0)  KST(9, A1)  KST(10, A2) KST(11, A3)
            KST(12, A0) KST(13, A1) KST(14, A2) KST(15, A3)
            KST(16, A0) KST(17, A1) KST(18, A2) KST(19, A3)
            KST(20, A0) KST(21, A1) KST(22, A2) KST(23, A3)
            KST(24, A0) KST(25, A1) KST(26, A2) KST(27, A3)
            KST(28, A0) KST(29, A1) KST(30, A2) KST(31, A3)
            float g0 = (A0.x + A1.x) + (A2.x + A3.x);
            float g1 = (A0.y + A1.y) + (A2.y + A3.y);
            float sA = sigm_f(g0);
            float u = sigm_f(half_sel * g1);
            float sB = (lane < 32) ? fmaf(2.f, u, -1.f) : u;
            float sf = __shfl(sA, (lane & 31) + 32);
            float so = __shfl(sB, (lane & 31) + 32);
            cst = fmaf(sf, cst, sA * sB);
            float hn = so * tanh_f(cst);
            h = hn;
            if (lane < H_) hc[t][dir * H_ + lane] = hn;
            t = tn;
        }
    }
    __syncthreads();   // hcat + Wl ready

    // ---- former k_final body; thread = its t; hcat reads -> LDS ----
    const int t = tid;
    float4 hr[16];
#pragma unroll
    for (int i = 0; i < 16; i++) hr[i] = *(const float4*)&hc[t][4 * i];
    float sc = 0.f;
    for (int j = 0; j < 64; j++) {
        float s = tab[j];
#pragma unroll
        for (int k4 = 0; k4 < 16; k4++) {
            float4 h4 = hr[k4];
            const float* wcol = &Wl[(4 * k4) * 64 + j];
            s += h4.x * wcol[0] + h4.y * wcol[64] + h4.z * wcol[128] + h4.w * wcol[192];
        }
        sc += tanhf(s) * tav[j];
    }
    sc *= (1.0f / 1.5f);
    float m = sc;
#pragma unroll
    for (int s_ = 1; s_ < 64; s_ <<= 1) m = fmaxf(m, __shfl_xor(m, s_));
    if (lane == 0) wred[wavid] = m;
    __syncthreads();
    m = fmaxf(fmaxf(wred[0], wred[1]), fmaxf(wred[2], wred[3]));
    float e = __expf(sc - m);
    float ssum = e;
#pragma unroll
    for (int s_ = 1; s_ < 64; s_ <<= 1) ssum += __shfl_xor(ssum, s_);
    __syncthreads();
    if (lane == 0) wred[wavid] = ssum;
    __syncthreads();
    float S = wred[0] + wred[1] + wred[2] + wred[3];
    al[t] = e / S;
    __syncthreads();
    // ctx partials: thread = (part = t>>6, o = t&63)
    {
        int o = t & 63, part = t >> 6;
        float cacc = 0.f;
        for (int tt = part * 64; tt < part * 64 + 64; tt++)
            cacc += al[tt] * hc[tt][o];
        ctxp[part][o] = cacc;
    }
    __syncthreads();
    if (t < 64) {
        float ctxo = ctxp[0][t] + ctxp[1][t] + ctxp[2][t] + ctxp[3][t];
        float sv = ctxo, sq = ctxo * ctxo;
#pragma unroll
        for (int s_ = 1; s_ < 64; s_ <<= 1) {
            sv += __shfl_xor(sv, s_);
            sq += __shfl_xor(sq, s_);
        }
        float mu = sv * (1.f / 64.f);
        float var = sq * (1.f / 64.f) - mu * mu;
        ctx[t] = (ctxo - mu) / sqrtf(var + 1e-5f) * lng[t] + lnb[t];
    }
    __syncthreads();
    if (t < 32) {
        float s = b1[t];
        for (int k = 0; k < 64; k++) s += ctx[k] * w1[k * 32 + t];
        a1s[t] = fmaxf(s, 0.f);
    }
    __syncthreads();
    if (t < 3) {
        float s = b2[t];
        for (int k = 0; k < 32; k++) s += a1s[k] * w2[k * 3 + t];
        out[b * 3 + t] = s;
    }
}

// ---------------------------------------------------------------------------
extern "C" void kernel_launch(void* const* d_in, const int* in_sizes, int n_in,
                              void* d_out, int out_size, void* d_ws, size_t ws_size,
                              hipStream_t stream) {
    const float* x          = (const float*)d_in[0];
    const float* spectral_w = (const float*)d_in[1];
    const float* gat_W      = (const float*)d_in[2];
    const float* gat_a      = (const float*)d_in[3];
    const float* pool_w     = (const float*)d_in[4];
    const float* pool_b     = (const float*)d_in[5];
    const float* lstm_Wi_f  = (const float*)d_in[6];
    const float* lstm_Wh_f  = (const float*)d_in[7];
    const float* lstm_b_f   = (const float*)d_in[8];
    const float* lstm_Wi_r  = (const float*)d_in[9];
    const float* lstm_Wh_r  = (const float*)d_in[10];
    const float* lstm_b_r   = (const float*)d_in[11];
    const float* ta_W       = (const float*)d_in[12];
    const float* ta_b       = (const float*)d_in[13];
    const float* ta_v       = (const float*)d_in[14];
    const float* ln_g       = (const float*)d_in[15];
    const float* ln_b       = (const float*)d_in[16];
    const float* fc1_w      = (const float*)d_in[17];
    const float* fc1_b      = (const float*)d_in[18];
    const float* fc2_w      = (const float*)d_in[19];
    const float* fc2_b      = (const float*)d_in[20];
    float* out = (float*)d_out;

    float* ws = (float*)d_ws;
    float* sw    = ws + 0;                         // 8192
    float* A     = ws + 8192;                      // 65536
    unsigned long long* amask = (unsigned long long*)(ws + 73728);  // 1024 u64
    float* Wh    = ws + 75776;                     // 8388608
    float* s1    = ws + 8464384;                   // 262144
    float* s2    = ws + 8726528;                   // 262144
    float* gx    = ws + 9119744;                   // 1048576 (row-major)

    hipMemsetAsync(A, 0, (size_t)C_ * C_ * B_ * sizeof(float), stream);
    k_sw<<<C_, 64, 0, stream>>>(spectral_w, sw);
    k_phase1<<<dim3(B_, T_ / TCP), 256, 0, stream>>>(x, sw, gat_W, gat_a, A, Wh, s1, s2);
    k_topk<<<B_, 64, 0, stream>>>(A, amask);
    k_gat<<<B_ * T_ / 4, 256, 0, stream>>>(Wh, s1, s2, amask, pool_w, pool_b,
                                           lstm_Wi_f, lstm_b_f, lstm_Wi_r, lstm_b_r, gx);
    k_lstm_final<<<B_, 256, (size_t)T_ * 64 * sizeof(float), stream>>>(
        gx, lstm_Wh_f, lstm_Wh_r, ta_W, ta_b, ta_v, ln_g, ln_b,
        fc1_w, fc1_b, fc2_w, fc2_b, out);
}